// Round 2
// baseline (1383.363 us; speedup 1.0000x reference)
//
#include <hip/hip_runtime.h>
#include <hip/hip_bf16.h>

// ---------------------------------------------------------------------------
// Sparse 3D conv network (MinkowskiNet-ish) on MI355X.
// Decomposition per conv layer:
//   y = h @ W[k=13]                      (dense self-GEMM, every point)
//   y += scatter-add over 26 sparse offsets (per-k gather-GEMM, ~2030 rows each)
// then BN stats (fp32 atomics) + BN-apply(+residual)+ReLU -> bf16 h.
// All GEMMs: v_mfma_f32_16x16x32_bf16, fp32 accum, XOR-swizzled LDS staging
// via global_load_lds (16B), m97-style 2-barrier K-loop.
// nbr_mask dtype (bool-bytes vs int32) is detected at runtime on device.
// ---------------------------------------------------------------------------

#define NPTS 65536
#define CHID 256
#define CAP  4096   // per-offset list capacity (expected ~2048)

typedef __bf16 bf16x8 __attribute__((ext_vector_type(8)));
typedef float  f32x4  __attribute__((ext_vector_type(4)));

__device__ __forceinline__ float bf2f(unsigned short u) {
    union { float f; unsigned v; } x; x.v = ((unsigned)u) << 16; return x.f;
}
__device__ __forceinline__ unsigned short f2bf(float f) {
    union { float f; unsigned v; } x; x.f = f;
    unsigned r = x.v + 0x7fffu + ((x.v >> 16) & 1u);
    return (unsigned short)(r >> 16);
}

__device__ __forceinline__ void gload16(const void* g, void* l) {
    __builtin_amdgcn_global_load_lds(
        (const __attribute__((address_space(1))) void*)g,
        (__attribute__((address_space(3))) void*)l, 16, 0, 0);
}

// mask accessor: mflag==1 -> bool bytes, mflag==0 -> int32
__device__ __forceinline__ bool mk(const void* mask, int mflag, size_t i) {
    if (mflag) return ((const unsigned char*)mask)[i] != 0;
    return ((const int*)mask)[i] != 0;
}

// ---------------------------------------------------------------------------
// Detect mask dtype: any nonzero byte at offset %4!=0 => bool-bytes (flag=1).
// Scans first 256 KiB (mask array is >=1.7 MB either way).
// ---------------------------------------------------------------------------
__global__ void detect_mask(const unsigned char* __restrict__ m, int* __restrict__ flag) {
    int t = blockIdx.x * 256 + threadIdx.x;   // 64 blocks * 256 threads
    int any = 0;
    for (int i = t; i < 262144; i += 64 * 256)
        if ((i & 3) && m[i]) any = 1;
    if (__any(any) && (threadIdx.x & 63) == 0 && any == 0) any = 0; // keep wave-uniformity trivial
    if (any) atomicOr(flag, 1);
}

// ---------------------------------------------------------------------------
// Weight repack: w_res [8][27][ci=256][co=256] f32 -> [8][27][co=256][ci=256] bf16
// ---------------------------------------------------------------------------
__global__ void pack_w(const float* __restrict__ w, unsigned short* __restrict__ wp) {
    __shared__ float tile[64][65];
    int m   = blockIdx.x;                 // matrix id 0..215
    int tci = (blockIdx.y >> 2) * 64;
    int tco = (blockIdx.y & 3) * 64;
    const float* src = w + (size_t)m * 65536;
    unsigned short* dst = wp + (size_t)m * 65536;
    int t = threadIdx.x, c = t & 63, rg = t >> 6;
    for (int r = rg; r < 64; r += 4)
        tile[r][c] = src[(size_t)(tci + r) * 256 + tco + c];
    __syncthreads();
    for (int r = rg; r < 64; r += 4)
        dst[(size_t)(tco + r) * 256 + tci + c] = f2bf(tile[c][r]);
}

// w_out [ci=256][co=128] f32 -> [co=128][ci=256] bf16
__global__ void pack_wout(const float* __restrict__ w, unsigned short* __restrict__ wp) {
    __shared__ float tile[64][65];
    int tco = blockIdx.x * 64, tci = blockIdx.y * 64;
    int t = threadIdx.x, c = t & 63, rg = t >> 6;
    for (int r = rg; r < 64; r += 4)
        tile[r][c] = w[(size_t)(tci + r) * 128 + tco + c];
    __syncthreads();
    for (int r = rg; r < 64; r += 4)
        wp[(size_t)(tco + r) * 256 + tci + c] = f2bf(tile[c][r]);
}

// ---------------------------------------------------------------------------
// Build per-offset CSR lists (k != 13). cnt must be pre-zeroed.
// ---------------------------------------------------------------------------
__global__ void build_lists(const int* __restrict__ idx, const void* __restrict__ mask,
                            const int* __restrict__ mflagp,
                            int* __restrict__ cnt, int* __restrict__ srcL, int* __restrict__ dstL) {
    int mflag = *mflagp;
    int n = blockIdx.x * 256 + threadIdx.x;
    for (int k = 0; k < 27; ++k) {
        if (k == 13) continue;
        if (mk(mask, mflag, (size_t)n * 27 + k)) {
            int k26 = (k < 13) ? k : k - 1;
            int p = atomicAdd(&cnt[k26], 1);
            if (p < CAP) {
                srcL[k26 * CAP + p] = idx[(size_t)n * 27 + k];
                dstL[k26 * CAP + p] = n;
            }
        }
    }
}

// ---------------------------------------------------------------------------
// Input conv: feats [N][3] f32 -> y [N][256] f32 (fp32 VALU, tiny compute)
// ---------------------------------------------------------------------------
__global__ void conv_in(const float* __restrict__ feats, const float* __restrict__ w, // [27][3][256]
                        const int* __restrict__ idx, const void* __restrict__ mask,
                        const int* __restrict__ mflagp, float* __restrict__ y) {
    int mflag = *mflagp;
    int n = blockIdx.x;
    int t = threadIdx.x;
    float acc = 0.f;
    for (int k = 0; k < 27; ++k) {
        if (mk(mask, mflag, (size_t)n * 27 + k)) {
            int j = idx[(size_t)n * 27 + k];
            float f0 = feats[j * 3 + 0], f1 = feats[j * 3 + 1], f2 = feats[j * 3 + 2];
            const float* wk = w + k * 3 * 256;
            acc += f0 * wk[t] + f1 * wk[256 + t] + f2 * wk[512 + t];
        }
    }
    y[(size_t)n * CHID + t] = acc;
}

// ---------------------------------------------------------------------------
// Conv GEMM. 64 rows x 256 co per block, 4 waves (each 64x64), K=256 in 4 steps.
// GATHER=false: self-offset (k=13), rows = blockIdx.x*64, direct store.
// GATHER=true : sparse offset k26=blockIdx.x, tile=blockIdx.y, atomic scatter.
// ---------------------------------------------------------------------------
template<bool GATHER>
__global__ __launch_bounds__(256, 2)
void conv_gemm(const unsigned short* __restrict__ hin,   // [N][256] bf16
               const unsigned short* __restrict__ Wp,    // [27][co=256][ci=256] bf16, conv base
               float* __restrict__ y,                    // [N][256] f32
               const int* __restrict__ cnt,
               const int* __restrict__ srcL,
               const int* __restrict__ dstL) {
    __shared__ __align__(16) char lds[8192 + 32768]; // A: 64x64 bf16 swz, B: 256co x 64ci bf16 swz
    __shared__ int ids_src[64];
    __shared__ int ids_dst[64];
    const int tid = threadIdx.x;
    const int lane = tid & 63;
    const int wave = tid >> 6;

    int k27, m0 = 0, tile = 0, c = 64;
    if (GATHER) {
        int k26 = blockIdx.x;
        k27 = (k26 < 13) ? k26 : k26 + 1;
        tile = blockIdx.y;
        c = min(cnt[k26], CAP);
        if (tile * 64 >= c) return;
        if (tid < 64) {
            int g = tile * 64 + tid;
            bool v = (g < c);
            ids_src[tid] = v ? srcL[k26 * CAP + g] : 0;
            ids_dst[tid] = v ? dstL[k26 * CAP + g] : -1;
        }
    } else {
        k27 = 13;
        m0 = blockIdx.x * 64;
    }
    const char* hbase = (const char*)hin;
    const char* wbase = (const char*)(Wp + (size_t)k27 * (CHID * CHID));

    f32x4 acc[4][4] = {};

    for (int ks = 0; ks < 4; ++ks) {
        int ci0 = ks * 64;
        __syncthreads();
        // stage: 40 x 1KB chunks (A 0..7, B 8..39), 10 per wave
        for (int i = 0; i < 10; ++i) {
            int chunk = wave * 10 + i;
            int o = chunk * 1024 + lane * 16;
            const char* src;
            if (o < 8192) {
                int row = o >> 7;
                int k2 = (o & 127) ^ ((row & 7) << 4);
                int grow = GATHER ? ids_src[row] : (m0 + row);
                src = hbase + (size_t)grow * 512 + ci0 * 2 + k2;
            } else {
                int bo = o - 8192;
                int corow = bo >> 7;
                int k2 = (bo & 127) ^ ((corow & 7) << 4);
                src = wbase + (size_t)corow * 512 + ci0 * 2 + k2;
            }
            gload16(src, lds + chunk * 1024);
        }
        __syncthreads();
        const char* A = lds;
        const char* B = lds + 8192;
        const int cw = wave * 64;
        for (int kk = 0; kk < 64; kk += 32) {
            int kl = kk + 8 * (lane >> 4);
            bf16x8 af[4], bfr[4];
            for (int mi = 0; mi < 4; ++mi) {
                int row = 16 * mi + (lane & 15);
                af[mi] = *(const bf16x8*)(A + row * 128 + ((2 * kl) ^ ((row & 7) << 4)));
            }
            for (int ni = 0; ni < 4; ++ni) {
                int corow = cw + 16 * ni + (lane & 15);
                bfr[ni] = *(const bf16x8*)(B + corow * 128 + ((2 * kl) ^ ((corow & 7) << 4)));
            }
            for (int mi = 0; mi < 4; ++mi)
                for (int ni = 0; ni < 4; ++ni)
                    acc[mi][ni] = __builtin_amdgcn_mfma_f32_16x16x32_bf16(af[mi], bfr[ni], acc[mi][ni], 0, 0, 0);
        }
    }

    const int cw = wave * 64;
    const int rq = 4 * (lane >> 4);
    const int colo = lane & 15;
    if (!GATHER) {
        for (int mi = 0; mi < 4; ++mi)
            for (int ni = 0; ni < 4; ++ni) {
                int col = cw + 16 * ni + colo;
                for (int r = 0; r < 4; ++r) {
                    int row = m0 + 16 * mi + rq + r;
                    y[(size_t)row * CHID + col] = acc[mi][ni][r];
                }
            }
    } else {
        for (int mi = 0; mi < 4; ++mi)
            for (int r = 0; r < 4; ++r) {
                int rl = 16 * mi + rq + r;
                int dst = ids_dst[rl];
                if (dst >= 0) {
                    for (int ni = 0; ni < 4; ++ni) {
                        int col = cw + 16 * ni + colo;
                        unsafeAtomicAdd(&y[(size_t)dst * CHID + col], acc[mi][ni][r]);
                    }
                }
            }
    }
}

// ---------------------------------------------------------------------------
// BN stats: per-channel sum & sumsq into st[0..255], st[256..511] (pre-zeroed)
// ---------------------------------------------------------------------------
__global__ void bn_stats(const float* __restrict__ y, float* __restrict__ st) {
    int t = threadIdx.x;
    int b = blockIdx.x;
    float s = 0.f, s2 = 0.f;
    size_t base = (size_t)b * 256 * CHID + t;
    for (int i = 0; i < 256; ++i) {
        float v = y[base + (size_t)i * CHID];
        s += v; s2 += v * v;
    }
    unsafeAtomicAdd(&st[t], s);
    unsafeAtomicAdd(&st[256 + t], s2);
}

// ---------------------------------------------------------------------------
// BN apply (+optional residual) + ReLU -> bf16
// ---------------------------------------------------------------------------
__global__ void bn_apply(const float* __restrict__ y, const float* __restrict__ st,
                         const float* __restrict__ g, const float* __restrict__ b,
                         const unsigned short* __restrict__ res, unsigned short* __restrict__ hout) {
    int t = threadIdx.x;
    float mean = st[t] * (1.f / NPTS);
    float var  = st[256 + t] * (1.f / NPTS) - mean * mean;
    float rstd = rsqrtf(var + 1e-5f);
    float sc = rstd * g[t];
    float bi = b[t] - mean * sc;
    size_t row0 = (size_t)blockIdx.x * 32;
    for (int i = 0; i < 32; ++i) {
        size_t off = (row0 + i) * CHID + t;
        float v = y[off] * sc + bi;
        if (res) v += bf2f(res[off]);
        v = fmaxf(v, 0.f);
        hout[off] = f2bf(v);
    }
}

// ---------------------------------------------------------------------------
// Output GEMM: out[N][128] = h[N][256] @ w_out. 128x128 tile, 4 waves 2x2.
// ---------------------------------------------------------------------------
__global__ __launch_bounds__(256, 2)
void gemm_out(const unsigned short* __restrict__ hin, const unsigned short* __restrict__ wop,
              float* __restrict__ out) {
    __shared__ __align__(16) char lds[16384 + 16384];
    const int tid = threadIdx.x, lane = tid & 63, wave = tid >> 6;
    const int m0 = blockIdx.x * 128;
    const char* hb = (const char*)hin;
    const char* wb = (const char*)wop;
    f32x4 acc[4][4] = {};
    for (int ks = 0; ks < 4; ++ks) {
        int ci0 = ks * 64;
        __syncthreads();
        for (int i = 0; i < 8; ++i) {
            int chunk = wave * 8 + i;
            int o = chunk * 1024 + lane * 16;
            const char* src;
            if (o < 16384) {
                int row = o >> 7;
                int k2 = (o & 127) ^ ((row & 7) << 4);
                src = hb + (size_t)(m0 + row) * 512 + ci0 * 2 + k2;
            } else {
                int bo = o - 16384;
                int corow = bo >> 7;
                int k2 = (bo & 127) ^ ((corow & 7) << 4);
                src = wb + (size_t)corow * 512 + ci0 * 2 + k2;
            }
            gload16(src, lds + chunk * 1024);
        }
        __syncthreads();
        const char* A = lds;
        const char* B = lds + 16384;
        const int wm = wave >> 1, wn = wave & 1;
        for (int kk = 0; kk < 64; kk += 32) {
            int kl = kk + 8 * (lane >> 4);
            bf16x8 af[4], bfr[4];
            for (int mi = 0; mi < 4; ++mi) {
                int row = 64 * wm + 16 * mi + (lane & 15);
                af[mi] = *(const bf16x8*)(A + row * 128 + ((2 * kl) ^ ((row & 7) << 4)));
            }
            for (int ni = 0; ni < 4; ++ni) {
                int corow = 64 * wn + 16 * ni + (lane & 15);
                bfr[ni] = *(const bf16x8*)(B + corow * 128 + ((2 * kl) ^ ((corow & 7) << 4)));
            }
            for (int mi = 0; mi < 4; ++mi)
                for (int ni = 0; ni < 4; ++ni)
                    acc[mi][ni] = __builtin_amdgcn_mfma_f32_16x16x32_bf16(af[mi], bfr[ni], acc[mi][ni], 0, 0, 0);
        }
    }
    const int wm = wave >> 1, wn = wave & 1;
    for (int mi = 0; mi < 4; ++mi)
        for (int ni = 0; ni < 4; ++ni) {
            int col = 64 * wn + 16 * ni + (lane & 15);
            for (int r = 0; r < 4; ++r) {
                int row = m0 + 64 * wm + 16 * mi + 4 * (lane >> 4) + r;
                out[(size_t)row * 128 + col] = acc[mi][ni][r];
            }
        }
}

// ---------------------------------------------------------------------------
// Workspace layout (bytes)
// ---------------------------------------------------------------------------
static const size_t OFF_Y    = 0;                         // 65536*256*4 = 64 MiB
static const size_t OFF_HA   = OFF_Y   + (size_t)NPTS * CHID * 4;
static const size_t OFF_HR   = OFF_HA  + (size_t)NPTS * CHID * 2;
static const size_t OFF_WP   = OFF_HR  + (size_t)NPTS * CHID * 2;
static const size_t OFF_WOP  = OFF_WP  + (size_t)8 * 27 * 65536 * 2;
static const size_t OFF_ST   = OFF_WOP + (size_t)128 * 256 * 2;
static const size_t OFF_CNT  = OFF_ST  + 9 * 512 * 4;
static const size_t OFF_FLAG = OFF_CNT + 112;             // inside the 128-byte CNT slab
static const size_t OFF_SRC  = OFF_CNT + 128;
static const size_t OFF_DST  = OFF_SRC + (size_t)26 * CAP * 4;

extern "C" void kernel_launch(void* const* d_in, const int* in_sizes, int n_in,
                              void* d_out, int out_size, void* d_ws, size_t ws_size,
                              hipStream_t stream) {
    const float* feats = (const float*)d_in[0];
    const float* w_in  = (const float*)d_in[1];
    const float* g_in  = (const float*)d_in[2];
    const float* b_in  = (const float*)d_in[3];
    const float* w_res = (const float*)d_in[4];
    const float* g_res = (const float*)d_in[5];
    const float* b_res = (const float*)d_in[6];
    const float* w_out = (const float*)d_in[7];
    const int*   nidx  = (const int*)d_in[8];
    const void*  nmask = (const void*)d_in[9];

    char* ws = (char*)d_ws;
    float*          Y    = (float*)(ws + OFF_Y);
    unsigned short* HA   = (unsigned short*)(ws + OFF_HA);
    unsigned short* HR   = (unsigned short*)(ws + OFF_HR);
    unsigned short* WP   = (unsigned short*)(ws + OFF_WP);
    unsigned short* WOP  = (unsigned short*)(ws + OFF_WOP);
    float*          ST   = (float*)(ws + OFF_ST);
    int*            CNT  = (int*)(ws + OFF_CNT);
    int*            MFLG = (int*)(ws + OFF_FLAG);
    int*            SRCL = (int*)(ws + OFF_SRC);
    int*            DSTL = (int*)(ws + OFF_DST);

    // zero BN stats (9 layers x 512 f32) + list counters + mask-dtype flag
    hipMemsetAsync(ws + OFF_ST, 0, 9 * 512 * 4 + 128, stream);

    detect_mask<<<64, 256, 0, stream>>>((const unsigned char*)nmask, MFLG);
    pack_w   <<<dim3(216, 16), 256, 0, stream>>>(w_res, WP);
    pack_wout<<<dim3(2, 4),    256, 0, stream>>>(w_out, WOP);
    build_lists<<<256, 256, 0, stream>>>(nidx, nmask, MFLG, CNT, SRCL, DSTL);

    conv_in<<<NPTS, 256, 0, stream>>>(feats, w_in, nidx, nmask, MFLG, Y);
    bn_stats<<<256, 256, 0, stream>>>(Y, ST);
    bn_apply<<<2048, 256, 0, stream>>>(Y, ST, g_in, b_in, nullptr, HA);

    for (int c8 = 0; c8 < 8; ++c8) {
        const unsigned short* hin = (c8 & 1) ? HR : HA;
        const unsigned short* wbase = WP + (size_t)c8 * 27 * 65536;
        conv_gemm<false><<<NPTS / 64, 256, 0, stream>>>(hin, wbase, Y, nullptr, nullptr, nullptr);
        conv_gemm<true><<<dim3(26, CAP / 64), 256, 0, stream>>>(hin, wbase, Y, CNT, SRCL, DSTL);
        float* st = ST + (size_t)(1 + c8) * 512;
        bn_stats<<<256, 256, 0, stream>>>(Y, st);
        if (c8 & 1) {
            bn_apply<<<2048, 256, 0, stream>>>(Y, st, g_res + c8 * 256, b_res + c8 * 256, HA, HA);
        } else {
            bn_apply<<<2048, 256, 0, stream>>>(Y, st, g_res + c8 * 256, b_res + c8 * 256, nullptr, HR);
        }
    }

    gemm_out<<<NPTS / 128, 256, 0, stream>>>(HA, WOP, (float*)d_out);
}

// Round 3
// 1159.575 us; speedup vs baseline: 1.1930x; 1.1930x over previous
//
#include <hip/hip_runtime.h>
#include <hip/hip_bf16.h>

// ---------------------------------------------------------------------------
// Sparse 3D conv network (MinkowskiNet-ish) on MI355X.
// Decomposition per conv layer:
//   y = h @ W[k=13]                      (dense self-GEMM, every point)
//   y += scatter-add over 26 sparse offsets (per-k gather-GEMM, ~2030 rows each)
// then BN stats (fp32 atomics) + BN-apply(+residual)+ReLU -> bf16 h.
// All GEMMs: v_mfma_f32_16x16x32_bf16, fp32 accum, XOR-swizzled LDS staging
// via global_load_lds (16B), m97-style 2-barrier K-loop.
// nbr_mask dtype (bool-bytes vs int32) is detected at runtime on device.
// Neighbor lists built with a deterministic 3-phase counting sort (no atomics).
// ---------------------------------------------------------------------------

#define NPTS 65536
#define CHID 256
#define CAP  4096   // per-offset list capacity (expected ~2030)
#define LBLK 256    // blocks in list-build phase (256 pts each)

typedef __bf16 bf16x8 __attribute__((ext_vector_type(8)));
typedef float  f32x4  __attribute__((ext_vector_type(4)));

__device__ __forceinline__ float bf2f(unsigned short u) {
    union { float f; unsigned v; } x; x.v = ((unsigned)u) << 16; return x.f;
}
__device__ __forceinline__ unsigned short f2bf(float f) {
    union { float f; unsigned v; } x; x.f = f;
    unsigned r = x.v + 0x7fffu + ((x.v >> 16) & 1u);
    return (unsigned short)(r >> 16);
}

__device__ __forceinline__ void gload16(const void* g, void* l) {
    __builtin_amdgcn_global_load_lds(
        (const __attribute__((address_space(1))) void*)g,
        (__attribute__((address_space(3))) void*)l, 16, 0, 0);
}

// mask accessor: mflag==1 -> bool bytes, mflag==0 -> int32
__device__ __forceinline__ bool mk(const void* mask, int mflag, size_t i) {
    if (mflag) return ((const unsigned char*)mask)[i] != 0;
    return ((const int*)mask)[i] != 0;
}

// ---------------------------------------------------------------------------
// Detect mask dtype: any nonzero byte at offset %4!=0 => bool-bytes (flag=1).
// ---------------------------------------------------------------------------
__global__ void detect_mask(const unsigned char* __restrict__ m, int* __restrict__ flag) {
    int t = blockIdx.x * 256 + threadIdx.x;   // 64 blocks * 256 threads
    int any = 0;
    for (int i = t; i < 262144; i += 64 * 256)
        if ((i & 3) && m[i]) any = 1;
    if (any) atomicOr(flag, 1);
}

// ---------------------------------------------------------------------------
// Weight repack: w_res [8][27][ci=256][co=256] f32 -> [8][27][co=256][ci=256] bf16
// ---------------------------------------------------------------------------
__global__ void pack_w(const float* __restrict__ w, unsigned short* __restrict__ wp) {
    __shared__ float tile[64][65];
    int m   = blockIdx.x;                 // matrix id 0..215
    int tci = (blockIdx.y >> 2) * 64;
    int tco = (blockIdx.y & 3) * 64;
    const float* src = w + (size_t)m * 65536;
    unsigned short* dst = wp + (size_t)m * 65536;
    int t = threadIdx.x, c = t & 63, rg = t >> 6;
    for (int r = rg; r < 64; r += 4)
        tile[r][c] = src[(size_t)(tci + r) * 256 + tco + c];
    __syncthreads();
    for (int r = rg; r < 64; r += 4)
        dst[(size_t)(tco + r) * 256 + tci + c] = f2bf(tile[c][r]);
}

// w_out [ci=256][co=128] f32 -> [co=128][ci=256] bf16
__global__ void pack_wout(const float* __restrict__ w, unsigned short* __restrict__ wp) {
    __shared__ float tile[64][65];
    int tco = blockIdx.x * 64, tci = blockIdx.y * 64;
    int t = threadIdx.x, c = t & 63, rg = t >> 6;
    for (int r = rg; r < 64; r += 4)
        tile[r][c] = w[(size_t)(tci + r) * 128 + tco + c];
    __syncthreads();
    for (int r = rg; r < 64; r += 4)
        wp[(size_t)(tco + r) * 256 + tci + c] = f2bf(tile[c][r]);
}

// ---------------------------------------------------------------------------
// Neighbor lists: deterministic 3-phase counting sort over (k, point) pairs.
// Phase 1: per-block counts per offset. Phase 2: exclusive scan -> bases+cnt.
// Phase 3: write entries at base + wave prefix + lane prefix. No atomics.
// ---------------------------------------------------------------------------
__global__ void count_lists(const void* __restrict__ mask, const int* __restrict__ mflagp,
                            int* __restrict__ blkcnt /*[26][LBLK]*/) {
    int mflag = *mflagp;
    int tid = threadIdx.x, lane = tid & 63;
    int n = blockIdx.x * 256 + tid;
    __shared__ int lc[26];
    if (tid < 26) lc[tid] = 0;
    __syncthreads();
    unsigned vb = 0;
    for (int k = 0; k < 27; ++k) {
        if (k == 13) continue;
        if (mk(mask, mflag, (size_t)n * 27 + k)) vb |= 1u << k;
    }
    for (int k26 = 0; k26 < 26; ++k26) {
        int k = (k26 < 13) ? k26 : k26 + 1;
        unsigned long long b = __ballot((vb >> k) & 1);
        if (lane == 0) atomicAdd(&lc[k26], __popcll(b));   // LDS atomic, 4 per k
    }
    __syncthreads();
    if (tid < 26) blkcnt[tid * LBLK + blockIdx.x] = lc[tid];
}

__global__ void scan_lists(const int* __restrict__ blkcnt, int* __restrict__ bases,
                           int* __restrict__ cnt) {
    int t = threadIdx.x;   // 1 block, 64 threads; t<26 active
    if (t < 26) {
        int s = 0;
        for (int b = 0; b < LBLK; ++b) {
            bases[t * LBLK + b] = s;
            s += blkcnt[t * LBLK + b];
        }
        cnt[t] = s;
    }
}

__global__ void fill_lists(const int* __restrict__ idx, const void* __restrict__ mask,
                           const int* __restrict__ mflagp, const int* __restrict__ bases,
                           int* __restrict__ srcL, int* __restrict__ dstL) {
    int mflag = *mflagp;
    int tid = threadIdx.x, lane = tid & 63, wave = tid >> 6;
    int n = blockIdx.x * 256 + tid;
    __shared__ int wcnt[4][26];
    unsigned vb = 0;
    for (int k = 0; k < 27; ++k) {
        if (k == 13) continue;
        if (mk(mask, mflag, (size_t)n * 27 + k)) vb |= 1u << k;
    }
    for (int k26 = 0; k26 < 26; ++k26) {
        int k = (k26 < 13) ? k26 : k26 + 1;
        unsigned long long b = __ballot((vb >> k) & 1);
        if (lane == 0) wcnt[wave][k26] = __popcll(b);
    }
    __syncthreads();
    for (int k26 = 0; k26 < 26; ++k26) {
        int k = (k26 < 13) ? k26 : k26 + 1;
        bool v = (vb >> k) & 1;
        unsigned long long b = __ballot(v);
        if (v) {
            int p = bases[k26 * LBLK + blockIdx.x] + __popcll(b & ((1ull << lane) - 1ull));
            for (int w = 0; w < wave; ++w) p += wcnt[w][k26];
            if (p < CAP) {
                srcL[k26 * CAP + p] = idx[(size_t)n * 27 + k];
                dstL[k26 * CAP + p] = n;
            }
        }
    }
}

// ---------------------------------------------------------------------------
// Input conv: feats [N][3] f32 -> y [N][256] f32 (fp32 VALU, tiny compute)
// ---------------------------------------------------------------------------
__global__ void conv_in(const float* __restrict__ feats, const float* __restrict__ w, // [27][3][256]
                        const int* __restrict__ idx, const void* __restrict__ mask,
                        const int* __restrict__ mflagp, float* __restrict__ y) {
    int mflag = *mflagp;
    int n = blockIdx.x;
    int t = threadIdx.x;
    float acc = 0.f;
    for (int k = 0; k < 27; ++k) {
        if (mk(mask, mflag, (size_t)n * 27 + k)) {
            int j = idx[(size_t)n * 27 + k];
            float f0 = feats[j * 3 + 0], f1 = feats[j * 3 + 1], f2 = feats[j * 3 + 2];
            const float* wk = w + k * 3 * 256;
            acc += f0 * wk[t] + f1 * wk[256 + t] + f2 * wk[512 + t];
        }
    }
    y[(size_t)n * CHID + t] = acc;
}

// ---------------------------------------------------------------------------
// Conv GEMM. 64 rows x 256 co per block, 4 waves (each 64x64), K=256 in 4 steps.
// GATHER=false: self-offset (k=13), rows = blockIdx.x*64, direct store.
// GATHER=true : sparse offset k26=blockIdx.x, tile=blockIdx.y, atomic scatter.
// ---------------------------------------------------------------------------
template<bool GATHER>
__global__ __launch_bounds__(256, 2)
void conv_gemm(const unsigned short* __restrict__ hin,   // [N][256] bf16
               const unsigned short* __restrict__ Wp,    // [27][co=256][ci=256] bf16, conv base
               float* __restrict__ y,                    // [N][256] f32
               const int* __restrict__ cnt,
               const int* __restrict__ srcL,
               const int* __restrict__ dstL) {
    __shared__ __align__(16) char lds[8192 + 32768]; // A: 64x64 bf16 swz, B: 256co x 64ci bf16 swz
    __shared__ int ids_src[64];
    __shared__ int ids_dst[64];
    const int tid = threadIdx.x;
    const int lane = tid & 63;
    const int wave = tid >> 6;

    int k27, m0 = 0, tile = 0, c = 64;
    if (GATHER) {
        int k26 = blockIdx.x;
        k27 = (k26 < 13) ? k26 : k26 + 1;
        tile = blockIdx.y;
        c = min(cnt[k26], CAP);
        if (tile * 64 >= c) return;
        if (tid < 64) {
            int g = tile * 64 + tid;
            bool v = (g < c);
            ids_src[tid] = v ? srcL[k26 * CAP + g] : 0;
            ids_dst[tid] = v ? dstL[k26 * CAP + g] : -1;
        }
    } else {
        k27 = 13;
        m0 = blockIdx.x * 64;
    }
    const char* hbase = (const char*)hin;
    const char* wbase = (const char*)(Wp + (size_t)k27 * (CHID * CHID));

    f32x4 acc[4][4] = {};

    for (int ks = 0; ks < 4; ++ks) {
        int ci0 = ks * 64;
        __syncthreads();
        // stage: 40 x 1KB chunks (A 0..7, B 8..39), 10 per wave
        for (int i = 0; i < 10; ++i) {
            int chunk = wave * 10 + i;
            int o = chunk * 1024 + lane * 16;
            const char* src;
            if (o < 8192) {
                int row = o >> 7;
                int k2 = (o & 127) ^ ((row & 7) << 4);
                int grow = GATHER ? ids_src[row] : (m0 + row);
                src = hbase + (size_t)grow * 512 + ci0 * 2 + k2;
            } else {
                int bo = o - 8192;
                int corow = bo >> 7;
                int k2 = (bo & 127) ^ ((corow & 7) << 4);
                src = wbase + (size_t)corow * 512 + ci0 * 2 + k2;
            }
            gload16(src, lds + chunk * 1024);
        }
        __syncthreads();
        const char* A = lds;
        const char* B = lds + 8192;
        const int cw = wave * 64;
        for (int kk = 0; kk < 64; kk += 32) {
            int kl = kk + 8 * (lane >> 4);
            bf16x8 af[4], bfr[4];
            for (int mi = 0; mi < 4; ++mi) {
                int row = 16 * mi + (lane & 15);
                af[mi] = *(const bf16x8*)(A + row * 128 + ((2 * kl) ^ ((row & 7) << 4)));
            }
            for (int ni = 0; ni < 4; ++ni) {
                int corow = cw + 16 * ni + (lane & 15);
                bfr[ni] = *(const bf16x8*)(B + corow * 128 + ((2 * kl) ^ ((corow & 7) << 4)));
            }
            for (int mi = 0; mi < 4; ++mi)
                for (int ni = 0; ni < 4; ++ni)
                    acc[mi][ni] = __builtin_amdgcn_mfma_f32_16x16x32_bf16(af[mi], bfr[ni], acc[mi][ni], 0, 0, 0);
        }
    }

    const int cw = wave * 64;
    const int rq = 4 * (lane >> 4);
    const int colo = lane & 15;
    if (!GATHER) {
        for (int mi = 0; mi < 4; ++mi)
            for (int ni = 0; ni < 4; ++ni) {
                int col = cw + 16 * ni + colo;
                for (int r = 0; r < 4; ++r) {
                    int row = m0 + 16 * mi + rq + r;
                    y[(size_t)row * CHID + col] = acc[mi][ni][r];
                }
            }
    } else {
        for (int mi = 0; mi < 4; ++mi)
            for (int r = 0; r < 4; ++r) {
                int rl = 16 * mi + rq + r;
                int dst = ids_dst[rl];
                if (dst >= 0) {
                    for (int ni = 0; ni < 4; ++ni) {
                        int col = cw + 16 * ni + colo;
                        unsafeAtomicAdd(&y[(size_t)dst * CHID + col], acc[mi][ni][r]);
                    }
                }
            }
    }
}

// ---------------------------------------------------------------------------
// BN stats: per-channel sum & sumsq into st[0..255], st[256..511] (pre-zeroed)
// ---------------------------------------------------------------------------
__global__ void bn_stats(const float* __restrict__ y, float* __restrict__ st) {
    int t = threadIdx.x;
    int b = blockIdx.x;
    float s = 0.f, s2 = 0.f;
    size_t base = (size_t)b * 256 * CHID + t;
    for (int i = 0; i < 256; ++i) {
        float v = y[base + (size_t)i * CHID];
        s += v; s2 += v * v;
    }
    unsafeAtomicAdd(&st[t], s);
    unsafeAtomicAdd(&st[256 + t], s2);
}

// ---------------------------------------------------------------------------
// BN apply (+optional residual) + ReLU -> bf16
// ---------------------------------------------------------------------------
__global__ void bn_apply(const float* __restrict__ y, const float* __restrict__ st,
                         const float* __restrict__ g, const float* __restrict__ b,
                         const unsigned short* __restrict__ res, unsigned short* __restrict__ hout) {
    int t = threadIdx.x;
    float mean = st[t] * (1.f / NPTS);
    float var  = st[256 + t] * (1.f / NPTS) - mean * mean;
    float rstd = rsqrtf(var + 1e-5f);
    float sc = rstd * g[t];
    float bi = b[t] - mean * sc;
    size_t row0 = (size_t)blockIdx.x * 32;
    for (int i = 0; i < 32; ++i) {
        size_t off = (row0 + i) * CHID + t;
        float v = y[off] * sc + bi;
        if (res) v += bf2f(res[off]);
        v = fmaxf(v, 0.f);
        hout[off] = f2bf(v);
    }
}

// ---------------------------------------------------------------------------
// Output GEMM: out[N][128] = h[N][256] @ w_out. 128x128 tile, 4 waves 2x2.
// ---------------------------------------------------------------------------
__global__ __launch_bounds__(256, 2)
void gemm_out(const unsigned short* __restrict__ hin, const unsigned short* __restrict__ wop,
              float* __restrict__ out) {
    __shared__ __align__(16) char lds[16384 + 16384];
    const int tid = threadIdx.x, lane = tid & 63, wave = tid >> 6;
    const int m0 = blockIdx.x * 128;
    const char* hb = (const char*)hin;
    const char* wb = (const char*)wop;
    f32x4 acc[4][4] = {};
    for (int ks = 0; ks < 4; ++ks) {
        int ci0 = ks * 64;
        __syncthreads();
        for (int i = 0; i < 8; ++i) {
            int chunk = wave * 8 + i;
            int o = chunk * 1024 + lane * 16;
            const char* src;
            if (o < 16384) {
                int row = o >> 7;
                int k2 = (o & 127) ^ ((row & 7) << 4);
                src = hb + (size_t)(m0 + row) * 512 + ci0 * 2 + k2;
            } else {
                int bo = o - 16384;
                int corow = bo >> 7;
                int k2 = (bo & 127) ^ ((corow & 7) << 4);
                src = wb + (size_t)corow * 512 + ci0 * 2 + k2;
            }
            gload16(src, lds + chunk * 1024);
        }
        __syncthreads();
        const char* A = lds;
        const char* B = lds + 16384;
        const int wm = wave >> 1, wn = wave & 1;
        for (int kk = 0; kk < 64; kk += 32) {
            int kl = kk + 8 * (lane >> 4);
            bf16x8 af[4], bfr[4];
            for (int mi = 0; mi < 4; ++mi) {
                int row = 64 * wm + 16 * mi + (lane & 15);
                af[mi] = *(const bf16x8*)(A + row * 128 + ((2 * kl) ^ ((row & 7) << 4)));
            }
            for (int ni = 0; ni < 4; ++ni) {
                int corow = 64 * wn + 16 * ni + (lane & 15);
                bfr[ni] = *(const bf16x8*)(B + corow * 128 + ((2 * kl) ^ ((corow & 7) << 4)));
            }
            for (int mi = 0; mi < 4; ++mi)
                for (int ni = 0; ni < 4; ++ni)
                    acc[mi][ni] = __builtin_amdgcn_mfma_f32_16x16x32_bf16(af[mi], bfr[ni], acc[mi][ni], 0, 0, 0);
        }
    }
    const int wm = wave >> 1, wn = wave & 1;
    for (int mi = 0; mi < 4; ++mi)
        for (int ni = 0; ni < 4; ++ni) {
            int col = 64 * wn + 16 * ni + (lane & 15);
            for (int r = 0; r < 4; ++r) {
                int row = m0 + 64 * wm + 16 * mi + 4 * (lane >> 4) + r;
                out[(size_t)row * 128 + col] = acc[mi][ni][r];
            }
        }
}

// ---------------------------------------------------------------------------
// Workspace layout (bytes)
// ---------------------------------------------------------------------------
static const size_t OFF_Y    = 0;                         // 65536*256*4 = 64 MiB
static const size_t OFF_HA   = OFF_Y   + (size_t)NPTS * CHID * 4;
static const size_t OFF_HR   = OFF_HA  + (size_t)NPTS * CHID * 2;
static const size_t OFF_WP   = OFF_HR  + (size_t)NPTS * CHID * 2;
static const size_t OFF_WOP  = OFF_WP  + (size_t)8 * 27 * 65536 * 2;
static const size_t OFF_ST   = OFF_WOP + (size_t)128 * 256 * 2;
static const size_t OFF_CNT  = OFF_ST  + 9 * 512 * 4;
static const size_t OFF_FLAG = OFF_CNT + 112;             // inside the 128-byte CNT slab
static const size_t OFF_SRC  = OFF_CNT + 128;
static const size_t OFF_DST  = OFF_SRC + (size_t)26 * CAP * 4;
static const size_t OFF_BLK  = OFF_DST + (size_t)26 * CAP * 4;
static const size_t OFF_BAS  = OFF_BLK + (size_t)26 * LBLK * 4;

extern "C" void kernel_launch(void* const* d_in, const int* in_sizes, int n_in,
                              void* d_out, int out_size, void* d_ws, size_t ws_size,
                              hipStream_t stream) {
    const float* feats = (const float*)d_in[0];
    const float* w_in  = (const float*)d_in[1];
    const float* g_in  = (const float*)d_in[2];
    const float* b_in  = (const float*)d_in[3];
    const float* w_res = (const float*)d_in[4];
    const float* g_res = (const float*)d_in[5];
    const float* b_res = (const float*)d_in[6];
    const float* w_out = (const float*)d_in[7];
    const int*   nidx  = (const int*)d_in[8];
    const void*  nmask = (const void*)d_in[9];

    char* ws = (char*)d_ws;
    float*          Y    = (float*)(ws + OFF_Y);
    unsigned short* HA   = (unsigned short*)(ws + OFF_HA);
    unsigned short* HR   = (unsigned short*)(ws + OFF_HR);
    unsigned short* WP   = (unsigned short*)(ws + OFF_WP);
    unsigned short* WOP  = (unsigned short*)(ws + OFF_WOP);
    float*          ST   = (float*)(ws + OFF_ST);
    int*            CNT  = (int*)(ws + OFF_CNT);
    int*            MFLG = (int*)(ws + OFF_FLAG);
    int*            SRCL = (int*)(ws + OFF_SRC);
    int*            DSTL = (int*)(ws + OFF_DST);
    int*            BLKC = (int*)(ws + OFF_BLK);
    int*            BASE = (int*)(ws + OFF_BAS);

    // zero BN stats (9 layers x 512 f32) + CNT slab + mask-dtype flag
    hipMemsetAsync(ws + OFF_ST, 0, 9 * 512 * 4 + 128, stream);

    detect_mask<<<64, 256, 0, stream>>>((const unsigned char*)nmask, MFLG);
    pack_w   <<<dim3(216, 16), 256, 0, stream>>>(w_res, WP);
    pack_wout<<<dim3(2, 4),    256, 0, stream>>>(w_out, WOP);

    count_lists<<<LBLK, 256, 0, stream>>>(nmask, MFLG, BLKC);
    scan_lists <<<1, 64, 0, stream>>>(BLKC, BASE, CNT);
    fill_lists <<<LBLK, 256, 0, stream>>>(nidx, nmask, MFLG, BASE, SRCL, DSTL);

    conv_in<<<NPTS, 256, 0, stream>>>(feats, w_in, nidx, nmask, MFLG, Y);
    bn_stats<<<256, 256, 0, stream>>>(Y, ST);
    bn_apply<<<2048, 256, 0, stream>>>(Y, ST, g_in, b_in, nullptr, HA);

    for (int c8 = 0; c8 < 8; ++c8) {
        const unsigned short* hin = (c8 & 1) ? HR : HA;
        const unsigned short* wbase = WP + (size_t)c8 * 27 * 65536;
        conv_gemm<false><<<NPTS / 64, 256, 0, stream>>>(hin, wbase, Y, nullptr, nullptr, nullptr);
        conv_gemm<true><<<dim3(26, CAP / 64), 256, 0, stream>>>(hin, wbase, Y, CNT, SRCL, DSTL);
        float* st = ST + (size_t)(1 + c8) * 512;
        bn_stats<<<256, 256, 0, stream>>>(Y, st);
        if (c8 & 1) {
            bn_apply<<<2048, 256, 0, stream>>>(Y, st, g_res + c8 * 256, b_res + c8 * 256, HA, HA);
        } else {
            bn_apply<<<2048, 256, 0, stream>>>(Y, st, g_res + c8 * 256, b_res + c8 * 256, nullptr, HR);
        }
    }

    gemm_out<<<NPTS / 128, 256, 0, stream>>>(HA, WOP, (float*)d_out);
}

// Round 4
// 1027.788 us; speedup vs baseline: 1.3460x; 1.1282x over previous
//
#include <hip/hip_runtime.h>
#include <hip/hip_bf16.h>

// ---------------------------------------------------------------------------
// Sparse 3D conv network (MinkowskiNet-ish) on MI355X.
//   y = h @ W[k=13]  (dense self-GEMM)  +  scatter over 26 sparse offsets
// BN stats (fp32 atomics) + BN-apply(+residual)+ReLU -> bf16 h.
// Y is bf16 (pair-packed stores; scatter via global_atomic_pk_add_bf16).
// Input conv = fused gather->LDS + MFMA GEMM (K=81 padded to 128).
// MFMA: v_mfma_f32_16x16x32_bf16, XOR-swizzled LDS, global_load_lds staging.
// ---------------------------------------------------------------------------

#define NPTS 65536
#define CHID 256
#define CAP  4096   // per-offset list capacity (expected ~2030)
#define LBLK 256    // blocks in list-build phase (256 pts each)

typedef __bf16 bf16x8 __attribute__((ext_vector_type(8)));
typedef float  f32x4  __attribute__((ext_vector_type(4)));

__device__ __forceinline__ float bf2f(unsigned short u) {
    union { float f; unsigned v; } x; x.v = ((unsigned)u) << 16; return x.f;
}
__device__ __forceinline__ unsigned short f2bf(float f) {
    union { float f; unsigned v; } x; x.f = f;
    unsigned r = x.v + 0x7fffu + ((x.v >> 16) & 1u);
    return (unsigned short)(r >> 16);
}

__device__ __forceinline__ void gload16(const void* g, void* l) {
    __builtin_amdgcn_global_load_lds(
        (const __attribute__((address_space(1))) void*)g,
        (__attribute__((address_space(3))) void*)l, 16, 0, 0);
}

// packed bf16x2 atomic add (CDNA4 global_atomic_pk_add_bf16)
__device__ __forceinline__ void atomic_pk_bf16(unsigned short* p, unsigned v) {
    asm volatile("global_atomic_pk_add_bf16 %0, %1, off" :: "v"(p), "v"(v) : "memory");
}

// mask accessor: mflag==1 -> bool bytes, mflag==0 -> int32
__device__ __forceinline__ bool mk(const void* mask, int mflag, size_t i) {
    if (mflag) return ((const unsigned char*)mask)[i] != 0;
    return ((const int*)mask)[i] != 0;
}

// ---------------------------------------------------------------------------
// Detect mask dtype: any nonzero byte at offset %4!=0 => bool-bytes (flag=1).
// ---------------------------------------------------------------------------
__global__ void detect_mask(const unsigned char* __restrict__ m, int* __restrict__ flag) {
    int t = blockIdx.x * 256 + threadIdx.x;
    int any = 0;
    for (int i = t; i < 262144; i += 64 * 256)
        if ((i & 3) && m[i]) any = 1;
    if (any) atomicOr(flag, 1);
}

// ---------------------------------------------------------------------------
// Weight repack: w_res [8][27][ci=256][co=256] f32 -> [8][27][co=256][ci=256] bf16
// ---------------------------------------------------------------------------
__global__ void pack_w(const float* __restrict__ w, unsigned short* __restrict__ wp) {
    __shared__ float tile[64][65];
    int m   = blockIdx.x;
    int tci = (blockIdx.y >> 2) * 64;
    int tco = (blockIdx.y & 3) * 64;
    const float* src = w + (size_t)m * 65536;
    unsigned short* dst = wp + (size_t)m * 65536;
    int t = threadIdx.x, c = t & 63, rg = t >> 6;
    for (int r = rg; r < 64; r += 4)
        tile[r][c] = src[(size_t)(tci + r) * 256 + tco + c];
    __syncthreads();
    for (int r = rg; r < 64; r += 4)
        dst[(size_t)(tco + r) * 256 + tci + c] = f2bf(tile[c][r]);
}

// w_out [ci=256][co=128] f32 -> [co=128][ci=256] bf16
__global__ void pack_wout(const float* __restrict__ w, unsigned short* __restrict__ wp) {
    __shared__ float tile[64][65];
    int tco = blockIdx.x * 64, tci = blockIdx.y * 64;
    int t = threadIdx.x, c = t & 63, rg = t >> 6;
    for (int r = rg; r < 64; r += 4)
        tile[r][c] = w[(size_t)(tci + r) * 128 + tco + c];
    __syncthreads();
    for (int r = rg; r < 64; r += 4)
        wp[(size_t)(tco + r) * 256 + tci + c] = f2bf(tile[c][r]);
}

// w_in [27][3][256] == [81][256] f32 -> WIN [co=256][kk=128] bf16 (kk>=81 zero)
__global__ void pack_win(const float* __restrict__ w, unsigned short* __restrict__ wp) {
    __shared__ float tile[64][65];
    int cot = blockIdx.x * 64, kkt = blockIdx.y * 64;
    int t = threadIdx.x, c = t & 63, rg = t >> 6;
    for (int r = rg; r < 64; r += 4) {
        int kk = kkt + r;
        tile[r][c] = (kk < 81) ? w[(size_t)kk * 256 + cot + c] : 0.f;
    }
    __syncthreads();
    for (int r = rg; r < 64; r += 4)
        wp[(size_t)(cot + r) * 128 + kkt + c] = f2bf(tile[c][r]);
}

// ---------------------------------------------------------------------------
// Neighbor lists: deterministic 3-phase counting sort (no global atomics).
// ---------------------------------------------------------------------------
__global__ void count_lists(const void* __restrict__ mask, const int* __restrict__ mflagp,
                            int* __restrict__ blkcnt /*[26][LBLK]*/) {
    int mflag = *mflagp;
    int tid = threadIdx.x, lane = tid & 63;
    int n = blockIdx.x * 256 + tid;
    __shared__ int lc[26];
    if (tid < 26) lc[tid] = 0;
    __syncthreads();
    unsigned vb = 0;
    for (int k = 0; k < 27; ++k) {
        if (k == 13) continue;
        if (mk(mask, mflag, (size_t)n * 27 + k)) vb |= 1u << k;
    }
    for (int k26 = 0; k26 < 26; ++k26) {
        int k = (k26 < 13) ? k26 : k26 + 1;
        unsigned long long b = __ballot((vb >> k) & 1);
        if (lane == 0) atomicAdd(&lc[k26], __popcll(b));
    }
    __syncthreads();
    if (tid < 26) blkcnt[tid * LBLK + blockIdx.x] = lc[tid];
}

__global__ void scan_lists(const int* __restrict__ blkcnt, int* __restrict__ bases,
                           int* __restrict__ cnt) {
    int t = threadIdx.x;
    if (t < 26) {
        int s = 0;
        for (int b = 0; b < LBLK; ++b) {
            bases[t * LBLK + b] = s;
            s += blkcnt[t * LBLK + b];
        }
        cnt[t] = s;
    }
}

__global__ void fill_lists(const int* __restrict__ idx, const void* __restrict__ mask,
                           const int* __restrict__ mflagp, const int* __restrict__ bases,
                           int* __restrict__ srcL, int* __restrict__ dstL) {
    int mflag = *mflagp;
    int tid = threadIdx.x, lane = tid & 63, wave = tid >> 6;
    int n = blockIdx.x * 256 + tid;
    __shared__ int wcnt[4][26];
    unsigned vb = 0;
    for (int k = 0; k < 27; ++k) {
        if (k == 13) continue;
        if (mk(mask, mflag, (size_t)n * 27 + k)) vb |= 1u << k;
    }
    for (int k26 = 0; k26 < 26; ++k26) {
        int k = (k26 < 13) ? k26 : k26 + 1;
        unsigned long long b = __ballot((vb >> k) & 1);
        if (lane == 0) wcnt[wave][k26] = __popcll(b);
    }
    __syncthreads();
    for (int k26 = 0; k26 < 26; ++k26) {
        int k = (k26 < 13) ? k26 : k26 + 1;
        bool v = (vb >> k) & 1;
        unsigned long long b = __ballot(v);
        if (v) {
            int p = bases[k26 * LBLK + blockIdx.x] + __popcll(b & ((1ull << lane) - 1ull));
            for (int w = 0; w < wave; ++w) p += wcnt[w][k26];
            if (p < CAP) {
                srcL[k26 * CAP + p] = idx[(size_t)n * 27 + k];
                dstL[k26 * CAP + p] = n;
            }
        }
    }
}

// ---------------------------------------------------------------------------
// Input conv as fused gather-GEMM: Y[64 rows][256 co] bf16 per block.
// A-tile [64][K=128] bf16 gathered sparsely into swizzled LDS; B = WIN.
// ---------------------------------------------------------------------------
__global__ __launch_bounds__(256, 2)
void convin_gemm(const float* __restrict__ feats, const unsigned short* __restrict__ win,
                 const int* __restrict__ idx, const void* __restrict__ mask,
                 const int* __restrict__ mflagp, unsigned short* __restrict__ yb) {
    __shared__ __align__(16) char A[16384];   // 64 rows x 256 B (swizzled)
    __shared__ __align__(16) char B[32768];   // 256 co x 128 B per K-step
    const int mflag = *mflagp;
    const int tid = threadIdx.x, lane = tid & 63, wave = tid >> 6;
    const int m0 = blockIdx.x * 64;

    // zero A
    for (int i = 0; i < 4; ++i)
        *(f32x4*)&A[tid * 64 + i * 16] = f32x4{0.f, 0.f, 0.f, 0.f};
    __syncthreads();

    // sparse gather into A: row = tid&63, k = (tid>>6) + 4*i
    {
        int row = tid & 63, g = tid >> 6;
        int n = m0 + row;
        int swz = (row & 7) << 4;
        for (int k = g; k < 27; k += 4) {
            if (mk(mask, mflag, (size_t)n * 27 + k)) {
                int j = idx[(size_t)n * 27 + k];
                float f0 = feats[j * 3 + 0], f1 = feats[j * 3 + 1], f2 = feats[j * 3 + 2];
                int b0 = 2 * (3 * k + 0), b1 = b0 + 2, b2 = b0 + 4;
                *(unsigned short*)&A[row * 256 + (b0 ^ swz)] = f2bf(f0);
                *(unsigned short*)&A[row * 256 + (b1 ^ swz)] = f2bf(f1);
                *(unsigned short*)&A[row * 256 + (b2 ^ swz)] = f2bf(f2);
            }
        }
    }

    const char* wb = (const char*)win;
    f32x4 acc[4][4] = {};

    for (int ks = 0; ks < 2; ++ks) {
        __syncthreads();
        // stage B half: 32 KB = 32 chunks of 1 KB, 8 per wave
        for (int i = 0; i < 8; ++i) {
            int chunk = wave * 8 + i;
            int o = chunk * 1024 + lane * 16;
            int corow = o >> 7;
            int inner = (o & 127) ^ ((corow & 7) << 4);
            gload16(wb + (size_t)corow * 256 + ks * 128 + inner, B + o);
        }
        __syncthreads();
        const int cw = wave * 64;
        for (int kk = 0; kk < 64; kk += 32) {
            int kl = kk + 8 * (lane >> 4);
            bf16x8 af[4], bfr[4];
            for (int mi = 0; mi < 4; ++mi) {
                int row = 16 * mi + (lane & 15);
                af[mi] = *(const bf16x8*)(A + row * 256 + ((ks * 128 + 2 * kl) ^ ((row & 7) << 4)));
            }
            for (int ni = 0; ni < 4; ++ni) {
                int corow = cw + 16 * ni + (lane & 15);
                bfr[ni] = *(const bf16x8*)(B + corow * 128 + ((2 * kl) ^ ((corow & 7) << 4)));
            }
            for (int mi = 0; mi < 4; ++mi)
                for (int ni = 0; ni < 4; ++ni)
                    acc[mi][ni] = __builtin_amdgcn_mfma_f32_16x16x32_bf16(af[mi], bfr[ni], acc[mi][ni], 0, 0, 0);
        }
    }

    // epilogue: pair-packed bf16 stores
    const int cw = wave * 64;
    const int rq = 4 * (lane >> 4);
    const int colo = lane & 15;
    for (int mi = 0; mi < 4; ++mi)
        for (int ni = 0; ni < 4; ++ni) {
            int col = cw + 16 * ni + colo;
            for (int r = 0; r < 4; ++r) {
                float v = acc[mi][ni][r];
                float o = __shfl_xor(v, 1);
                if ((lane & 1) == 0) {
                    unsigned pk = (unsigned)f2bf(v) | ((unsigned)f2bf(o) << 16);
                    int row = m0 + 16 * mi + rq + r;
                    *(unsigned*)&yb[(size_t)row * CHID + col] = pk;
                }
            }
        }
}

// ---------------------------------------------------------------------------
// Conv GEMM. 64 rows x 256 co per block, 4 waves, K=256 in 4 steps. Y bf16.
// GATHER=false: self-offset, direct pair-packed store.
// GATHER=true : sparse offset, pk-bf16 atomic scatter.
// ---------------------------------------------------------------------------
template<bool GATHER>
__global__ __launch_bounds__(256, 2)
void conv_gemm(const unsigned short* __restrict__ hin,   // [N][256] bf16
               const unsigned short* __restrict__ Wp,    // [27][co=256][ci=256] bf16
               unsigned short* __restrict__ yb,          // [N][256] bf16
               const int* __restrict__ cnt,
               const int* __restrict__ srcL,
               const int* __restrict__ dstL) {
    __shared__ __align__(16) char lds[8192 + 32768];
    __shared__ int ids_src[64];
    __shared__ int ids_dst[64];
    const int tid = threadIdx.x;
    const int lane = tid & 63;
    const int wave = tid >> 6;

    int k27, m0 = 0, tile = 0, c = 64;
    if (GATHER) {
        int k26 = blockIdx.x;
        k27 = (k26 < 13) ? k26 : k26 + 1;
        tile = blockIdx.y;
        c = min(cnt[k26], CAP);
        if (tile * 64 >= c) return;
        if (tid < 64) {
            int g = tile * 64 + tid;
            bool v = (g < c);
            ids_src[tid] = v ? srcL[k26 * CAP + g] : 0;
            ids_dst[tid] = v ? dstL[k26 * CAP + g] : -1;
        }
    } else {
        k27 = 13;
        m0 = blockIdx.x * 64;
    }
    const char* hbase = (const char*)hin;
    const char* wbase = (const char*)(Wp + (size_t)k27 * (CHID * CHID));

    f32x4 acc[4][4] = {};

    for (int ks = 0; ks < 4; ++ks) {
        int ci0 = ks * 64;
        __syncthreads();
        for (int i = 0; i < 10; ++i) {
            int chunk = wave * 10 + i;
            int o = chunk * 1024 + lane * 16;
            const char* src;
            if (o < 8192) {
                int row = o >> 7;
                int k2 = (o & 127) ^ ((row & 7) << 4);
                int grow = GATHER ? ids_src[row] : (m0 + row);
                src = hbase + (size_t)grow * 512 + ci0 * 2 + k2;
            } else {
                int bo = o - 8192;
                int corow = bo >> 7;
                int k2 = (bo & 127) ^ ((corow & 7) << 4);
                src = wbase + (size_t)corow * 512 + ci0 * 2 + k2;
            }
            gload16(src, lds + chunk * 1024);
        }
        __syncthreads();
        const char* A = lds;
        const char* B = lds + 8192;
        const int cw = wave * 64;
        for (int kk = 0; kk < 64; kk += 32) {
            int kl = kk + 8 * (lane >> 4);
            bf16x8 af[4], bfr[4];
            for (int mi = 0; mi < 4; ++mi) {
                int row = 16 * mi + (lane & 15);
                af[mi] = *(const bf16x8*)(A + row * 128 + ((2 * kl) ^ ((row & 7) << 4)));
            }
            for (int ni = 0; ni < 4; ++ni) {
                int corow = cw + 16 * ni + (lane & 15);
                bfr[ni] = *(const bf16x8*)(B + corow * 128 + ((2 * kl) ^ ((corow & 7) << 4)));
            }
            for (int mi = 0; mi < 4; ++mi)
                for (int ni = 0; ni < 4; ++ni)
                    acc[mi][ni] = __builtin_amdgcn_mfma_f32_16x16x32_bf16(af[mi], bfr[ni], acc[mi][ni], 0, 0, 0);
        }
    }

    const int cw = wave * 64;
    const int rq = 4 * (lane >> 4);
    const int colo = lane & 15;
    for (int mi = 0; mi < 4; ++mi)
        for (int ni = 0; ni < 4; ++ni) {
            int col = cw + 16 * ni + colo;
            for (int r = 0; r < 4; ++r) {
                float v = acc[mi][ni][r];
                float o = __shfl_xor(v, 1);
                if ((lane & 1) == 0) {
                    unsigned pk = (unsigned)f2bf(v) | ((unsigned)f2bf(o) << 16);
                    if (!GATHER) {
                        int row = m0 + 16 * mi + rq + r;
                        *(unsigned*)&yb[(size_t)row * CHID + col] = pk;
                    } else {
                        int rl = 16 * mi + rq + r;
                        int dst = ids_dst[rl];
                        if (dst >= 0)
                            atomic_pk_bf16(&yb[(size_t)dst * CHID + col], pk);
                    }
                }
            }
        }
}

// ---------------------------------------------------------------------------
// BN stats on bf16 Y: per-channel sum & sumsq into st[0..255], st[256..511]
// ---------------------------------------------------------------------------
__global__ void bn_stats(const unsigned short* __restrict__ yb, float* __restrict__ st) {
    int t = threadIdx.x;
    int b = blockIdx.x;
    float s = 0.f, s2 = 0.f;
    size_t base = (size_t)b * 256 * CHID + t;
    for (int i = 0; i < 256; ++i) {
        float v = bf2f(yb[base + (size_t)i * CHID]);
        s += v; s2 += v * v;
    }
    unsafeAtomicAdd(&st[t], s);
    unsafeAtomicAdd(&st[256 + t], s2);
}

// ---------------------------------------------------------------------------
// BN apply (+optional residual) + ReLU -> bf16
// ---------------------------------------------------------------------------
__global__ void bn_apply(const unsigned short* __restrict__ yb, const float* __restrict__ st,
                         const float* __restrict__ g, const float* __restrict__ b,
                         const unsigned short* __restrict__ res, unsigned short* __restrict__ hout) {
    int t = threadIdx.x;
    float mean = st[t] * (1.f / NPTS);
    float var  = st[256 + t] * (1.f / NPTS) - mean * mean;
    float rstd = rsqrtf(var + 1e-5f);
    float sc = rstd * g[t];
    float bi = b[t] - mean * sc;
    size_t row0 = (size_t)blockIdx.x * 32;
    for (int i = 0; i < 32; ++i) {
        size_t off = (row0 + i) * CHID + t;
        float v = bf2f(yb[off]) * sc + bi;
        if (res) v += bf2f(res[off]);
        v = fmaxf(v, 0.f);
        hout[off] = f2bf(v);
    }
}

// ---------------------------------------------------------------------------
// Output GEMM: out[N][128] = h[N][256] @ w_out. 128x128 tile, 4 waves 2x2.
// ---------------------------------------------------------------------------
__global__ __launch_bounds__(256, 2)
void gemm_out(const unsigned short* __restrict__ hin, const unsigned short* __restrict__ wop,
              float* __restrict__ out) {
    __shared__ __align__(16) char lds[16384 + 16384];
    const int tid = threadIdx.x, lane = tid & 63, wave = tid >> 6;
    const int m0 = blockIdx.x * 128;
    const char* hb = (const char*)hin;
    const char* wb = (const char*)wop;
    f32x4 acc[4][4] = {};
    for (int ks = 0; ks < 4; ++ks) {
        int ci0 = ks * 64;
        __syncthreads();
        for (int i = 0; i < 8; ++i) {
            int chunk = wave * 8 + i;
            int o = chunk * 1024 + lane * 16;
            const char* src;
            if (o < 16384) {
                int row = o >> 7;
                int k2 = (o & 127) ^ ((row & 7) << 4);
                src = hb + (size_t)(m0 + row) * 512 + ci0 * 2 + k2;
            } else {
                int bo = o - 16384;
                int corow = bo >> 7;
                int k2 = (bo & 127) ^ ((corow & 7) << 4);
                src = wb + (size_t)corow * 512 + ci0 * 2 + k2;
            }
            gload16(src, lds + chunk * 1024);
        }
        __syncthreads();
        const char* A = lds;
        const char* B = lds + 16384;
        const int wm = wave >> 1, wn = wave & 1;
        for (int kk = 0; kk < 64; kk += 32) {
            int kl = kk + 8 * (lane >> 4);
            bf16x8 af[4], bfr[4];
            for (int mi = 0; mi < 4; ++mi) {
                int row = 64 * wm + 16 * mi + (lane & 15);
                af[mi] = *(const bf16x8*)(A + row * 128 + ((2 * kl) ^ ((row & 7) << 4)));
            }
            for (int ni = 0; ni < 4; ++ni) {
                int corow = 64 * wn + 16 * ni + (lane & 15);
                bfr[ni] = *(const bf16x8*)(B + corow * 128 + ((2 * kl) ^ ((corow & 7) << 4)));
            }
            for (int mi = 0; mi < 4; ++mi)
                for (int ni = 0; ni < 4; ++ni)
                    acc[mi][ni] = __builtin_amdgcn_mfma_f32_16x16x32_bf16(af[mi], bfr[ni], acc[mi][ni], 0, 0, 0);
        }
    }
    const int wm = wave >> 1, wn = wave & 1;
    for (int mi = 0; mi < 4; ++mi)
        for (int ni = 0; ni < 4; ++ni) {
            int col = 64 * wn + 16 * ni + (lane & 15);
            for (int r = 0; r < 4; ++r) {
                int row = m0 + 64 * wm + 16 * mi + 4 * (lane >> 4) + r;
                out[(size_t)row * 128 + col] = acc[mi][ni][r];
            }
        }
}

// ---------------------------------------------------------------------------
// Workspace layout (bytes)
// ---------------------------------------------------------------------------
static const size_t OFF_Y    = 0;                         // bf16 Y: 32 MiB
static const size_t OFF_HA   = OFF_Y   + (size_t)NPTS * CHID * 2;
static const size_t OFF_HR   = OFF_HA  + (size_t)NPTS * CHID * 2;
static const size_t OFF_WP   = OFF_HR  + (size_t)NPTS * CHID * 2;
static const size_t OFF_WOP  = OFF_WP  + (size_t)8 * 27 * 65536 * 2;
static const size_t OFF_WIN  = OFF_WOP + (size_t)128 * 256 * 2;
static const size_t OFF_ST   = OFF_WIN + (size_t)256 * 128 * 2;
static const size_t OFF_CNT  = OFF_ST  + 9 * 512 * 4;
static const size_t OFF_FLAG = OFF_CNT + 112;
static const size_t OFF_SRC  = OFF_CNT + 128;
static const size_t OFF_DST  = OFF_SRC + (size_t)26 * CAP * 4;
static const size_t OFF_BLK  = OFF_DST + (size_t)26 * CAP * 4;
static const size_t OFF_BAS  = OFF_BLK + (size_t)26 * LBLK * 4;

extern "C" void kernel_launch(void* const* d_in, const int* in_sizes, int n_in,
                              void* d_out, int out_size, void* d_ws, size_t ws_size,
                              hipStream_t stream) {
    const float* feats = (const float*)d_in[0];
    const float* w_in  = (const float*)d_in[1];
    const float* g_in  = (const float*)d_in[2];
    const float* b_in  = (const float*)d_in[3];
    const float* w_res = (const float*)d_in[4];
    const float* g_res = (const float*)d_in[5];
    const float* b_res = (const float*)d_in[6];
    const float* w_out = (const float*)d_in[7];
    const int*   nidx  = (const int*)d_in[8];
    const void*  nmask = (const void*)d_in[9];

    char* ws = (char*)d_ws;
    unsigned short* Yb   = (unsigned short*)(ws + OFF_Y);
    unsigned short* HA   = (unsigned short*)(ws + OFF_HA);
    unsigned short* HR   = (unsigned short*)(ws + OFF_HR);
    unsigned short* WP   = (unsigned short*)(ws + OFF_WP);
    unsigned short* WOP  = (unsigned short*)(ws + OFF_WOP);
    unsigned short* WIN  = (unsigned short*)(ws + OFF_WIN);
    float*          ST   = (float*)(ws + OFF_ST);
    int*            CNT  = (int*)(ws + OFF_CNT);
    int*            MFLG = (int*)(ws + OFF_FLAG);
    int*            SRCL = (int*)(ws + OFF_SRC);
    int*            DSTL = (int*)(ws + OFF_DST);
    int*            BLKC = (int*)(ws + OFF_BLK);
    int*            BASE = (int*)(ws + OFF_BAS);

    // zero BN stats (9 layers x 512 f32) + CNT slab + mask-dtype flag
    hipMemsetAsync(ws + OFF_ST, 0, 9 * 512 * 4 + 128, stream);

    detect_mask<<<64, 256, 0, stream>>>((const unsigned char*)nmask, MFLG);
    pack_w   <<<dim3(216, 16), 256, 0, stream>>>(w_res, WP);
    pack_wout<<<dim3(2, 4),    256, 0, stream>>>(w_out, WOP);
    pack_win <<<dim3(4, 2),    256, 0, stream>>>(w_in, WIN);

    count_lists<<<LBLK, 256, 0, stream>>>(nmask, MFLG, BLKC);
    scan_lists <<<1, 64, 0, stream>>>(BLKC, BASE, CNT);
    fill_lists <<<LBLK, 256, 0, stream>>>(nidx, nmask, MFLG, BASE, SRCL, DSTL);

    convin_gemm<<<NPTS / 64, 256, 0, stream>>>(feats, WIN, nidx, nmask, MFLG, Yb);
    bn_stats<<<256, 256, 0, stream>>>(Yb, ST);
    bn_apply<<<2048, 256, 0, stream>>>(Yb, ST, g_in, b_in, nullptr, HA);

    for (int c8 = 0; c8 < 8; ++c8) {
        const unsigned short* hin = (c8 & 1) ? HR : HA;
        const unsigned short* wbase = WP + (size_t)c8 * 27 * 65536;
        conv_gemm<false><<<NPTS / 64, 256, 0, stream>>>(hin, wbase, Yb, nullptr, nullptr, nullptr);
        conv_gemm<true><<<dim3(26, CAP / 64), 256, 0, stream>>>(hin, wbase, Yb, CNT, SRCL, DSTL);
        float* st = ST + (size_t)(1 + c8) * 512;
        bn_stats<<<256, 256, 0, stream>>>(Yb, st);
        if (c8 & 1) {
            bn_apply<<<2048, 256, 0, stream>>>(Yb, st, g_res + c8 * 256, b_res + c8 * 256, HA, HA);
        } else {
            bn_apply<<<2048, 256, 0, stream>>>(Yb, st, g_res + c8 * 256, b_res + c8 * 256, nullptr, HR);
        }
    }

    gemm_out<<<NPTS / 128, 256, 0, stream>>>(HA, WOP, (float*)d_out);
}

// Round 5
// 967.972 us; speedup vs baseline: 1.4291x; 1.0618x over previous
//
#include <hip/hip_runtime.h>
#include <hip/hip_bf16.h>

// ---------------------------------------------------------------------------
// Sparse 3D conv network (MinkowskiNet-ish) on MI355X.
//   y = h @ W[k=13]  (dense self-GEMM)  +  scatter over 26 sparse offsets
// BN stats (fp32 atomics) + BN-apply(+residual)+ReLU -> bf16 h.
// Y is bf16 (pair-packed stores; scatter via global_atomic_pk_add_bf16).
// Conv GEMM: 256x256 tile, BK=64, 8 waves, double-buffered 2-phase
// (STAGE(next) issued before COMPUTE(cur), one drain per K-step).
// MFMA: v_mfma_f32_16x16x32_bf16, XOR-swizzled LDS, global_load_lds staging.
// ---------------------------------------------------------------------------

#define NPTS 65536
#define CHID 256
#define CAP  4096   // per-offset list capacity (expected ~2030)
#define LBLK 256    // blocks in list-build phase (256 pts each)

typedef __bf16 bf16x8 __attribute__((ext_vector_type(8)));
typedef float  f32x4  __attribute__((ext_vector_type(4)));

__device__ __forceinline__ float bf2f(unsigned short u) {
    union { float f; unsigned v; } x; x.v = ((unsigned)u) << 16; return x.f;
}
__device__ __forceinline__ unsigned short f2bf(float f) {
    union { float f; unsigned v; } x; x.f = f;
    unsigned r = x.v + 0x7fffu + ((x.v >> 16) & 1u);
    return (unsigned short)(r >> 16);
}

__device__ __forceinline__ void gload16(const void* g, void* l) {
    __builtin_amdgcn_global_load_lds(
        (const __attribute__((address_space(1))) void*)g,
        (__attribute__((address_space(3))) void*)l, 16, 0, 0);
}

// packed bf16x2 atomic add (CDNA4 global_atomic_pk_add_bf16)
__device__ __forceinline__ void atomic_pk_bf16(unsigned short* p, unsigned v) {
    asm volatile("global_atomic_pk_add_bf16 %0, %1, off" :: "v"(p), "v"(v) : "memory");
}

// mask accessor: mflag==1 -> bool bytes, mflag==0 -> int32
__device__ __forceinline__ bool mk(const void* mask, int mflag, size_t i) {
    if (mflag) return ((const unsigned char*)mask)[i] != 0;
    return ((const int*)mask)[i] != 0;
}

// ---------------------------------------------------------------------------
// Detect mask dtype: any nonzero byte at offset %4!=0 => bool-bytes (flag=1).
// ---------------------------------------------------------------------------
__global__ void detect_mask(const unsigned char* __restrict__ m, int* __restrict__ flag) {
    int t = blockIdx.x * 256 + threadIdx.x;
    int any = 0;
    for (int i = t; i < 262144; i += 64 * 256)
        if ((i & 3) && m[i]) any = 1;
    if (any) atomicOr(flag, 1);
}

// ---------------------------------------------------------------------------
// Weight repack: w_res [8][27][ci=256][co=256] f32 -> [8][27][co=256][ci=256] bf16
// ---------------------------------------------------------------------------
__global__ void pack_w(const float* __restrict__ w, unsigned short* __restrict__ wp) {
    __shared__ float tile[64][65];
    int m   = blockIdx.x;
    int tci = (blockIdx.y >> 2) * 64;
    int tco = (blockIdx.y & 3) * 64;
    const float* src = w + (size_t)m * 65536;
    unsigned short* dst = wp + (size_t)m * 65536;
    int t = threadIdx.x, c = t & 63, rg = t >> 6;
    for (int r = rg; r < 64; r += 4)
        tile[r][c] = src[(size_t)(tci + r) * 256 + tco + c];
    __syncthreads();
    for (int r = rg; r < 64; r += 4)
        dst[(size_t)(tco + r) * 256 + tci + c] = f2bf(tile[c][r]);
}

// w_out [ci=256][co=128] f32 -> [co=128][ci=256] bf16
__global__ void pack_wout(const float* __restrict__ w, unsigned short* __restrict__ wp) {
    __shared__ float tile[64][65];
    int tco = blockIdx.x * 64, tci = blockIdx.y * 64;
    int t = threadIdx.x, c = t & 63, rg = t >> 6;
    for (int r = rg; r < 64; r += 4)
        tile[r][c] = w[(size_t)(tci + r) * 128 + tco + c];
    __syncthreads();
    for (int r = rg; r < 64; r += 4)
        wp[(size_t)(tco + r) * 256 + tci + c] = f2bf(tile[c][r]);
}

// w_in [27][3][256] == [81][256] f32 -> WIN [co=256][kk=128] bf16 (kk>=81 zero)
__global__ void pack_win(const float* __restrict__ w, unsigned short* __restrict__ wp) {
    __shared__ float tile[64][65];
    int cot = blockIdx.x * 64, kkt = blockIdx.y * 64;
    int t = threadIdx.x, c = t & 63, rg = t >> 6;
    for (int r = rg; r < 64; r += 4) {
        int kk = kkt + r;
        tile[r][c] = (kk < 81) ? w[(size_t)kk * 256 + cot + c] : 0.f;
    }
    __syncthreads();
    for (int r = rg; r < 64; r += 4)
        wp[(size_t)(cot + r) * 128 + kkt + c] = f2bf(tile[c][r]);
}

// ---------------------------------------------------------------------------
// Neighbor lists: deterministic 3-phase counting sort (no global atomics).
// ---------------------------------------------------------------------------
__global__ void count_lists(const void* __restrict__ mask, const int* __restrict__ mflagp,
                            int* __restrict__ blkcnt /*[26][LBLK]*/) {
    int mflag = *mflagp;
    int tid = threadIdx.x, lane = tid & 63;
    int n = blockIdx.x * 256 + tid;
    __shared__ int lc[26];
    if (tid < 26) lc[tid] = 0;
    __syncthreads();
    unsigned vb = 0;
    for (int k = 0; k < 27; ++k) {
        if (k == 13) continue;
        if (mk(mask, mflag, (size_t)n * 27 + k)) vb |= 1u << k;
    }
    for (int k26 = 0; k26 < 26; ++k26) {
        int k = (k26 < 13) ? k26 : k26 + 1;
        unsigned long long b = __ballot((vb >> k) & 1);
        if (lane == 0) atomicAdd(&lc[k26], __popcll(b));
    }
    __syncthreads();
    if (tid < 26) blkcnt[tid * LBLK + blockIdx.x] = lc[tid];
}

__global__ void scan_lists(const int* __restrict__ blkcnt, int* __restrict__ bases,
                           int* __restrict__ cnt) {
    int t = threadIdx.x;
    if (t < 26) {
        int s = 0;
        for (int b = 0; b < LBLK; ++b) {
            bases[t * LBLK + b] = s;
            s += blkcnt[t * LBLK + b];
        }
        cnt[t] = s;
    }
}

__global__ void fill_lists(const int* __restrict__ idx, const void* __restrict__ mask,
                           const int* __restrict__ mflagp, const int* __restrict__ bases,
                           int* __restrict__ srcL, int* __restrict__ dstL) {
    int mflag = *mflagp;
    int tid = threadIdx.x, lane = tid & 63, wave = tid >> 6;
    int n = blockIdx.x * 256 + tid;
    __shared__ int wcnt[4][26];
    unsigned vb = 0;
    for (int k = 0; k < 27; ++k) {
        if (k == 13) continue;
        if (mk(mask, mflag, (size_t)n * 27 + k)) vb |= 1u << k;
    }
    for (int k26 = 0; k26 < 26; ++k26) {
        int k = (k26 < 13) ? k26 : k26 + 1;
        unsigned long long b = __ballot((vb >> k) & 1);
        if (lane == 0) wcnt[wave][k26] = __popcll(b);
    }
    __syncthreads();
    for (int k26 = 0; k26 < 26; ++k26) {
        int k = (k26 < 13) ? k26 : k26 + 1;
        bool v = (vb >> k) & 1;
        unsigned long long b = __ballot(v);
        if (v) {
            int p = bases[k26 * LBLK + blockIdx.x] + __popcll(b & ((1ull << lane) - 1ull));
            for (int w = 0; w < wave; ++w) p += wcnt[w][k26];
            if (p < CAP) {
                srcL[k26 * CAP + p] = idx[(size_t)n * 27 + k];
                dstL[k26 * CAP + p] = n;
            }
        }
    }
}

// ---------------------------------------------------------------------------
// Input conv as fused gather-GEMM: Y[64 rows][256 co] bf16 per block.
// ---------------------------------------------------------------------------
__global__ __launch_bounds__(256, 2)
void convin_gemm(const float* __restrict__ feats, const unsigned short* __restrict__ win,
                 const int* __restrict__ idx, const void* __restrict__ mask,
                 const int* __restrict__ mflagp, unsigned short* __restrict__ yb) {
    __shared__ __align__(16) char A[16384];   // 64 rows x 256 B (swizzled)
    __shared__ __align__(16) char B[32768];   // 256 co x 128 B per K-step
    const int mflag = *mflagp;
    const int tid = threadIdx.x, lane = tid & 63, wave = tid >> 6;
    const int m0 = blockIdx.x * 64;

    for (int i = 0; i < 4; ++i)
        *(f32x4*)&A[tid * 64 + i * 16] = f32x4{0.f, 0.f, 0.f, 0.f};
    __syncthreads();

    {
        int row = tid & 63, g = tid >> 6;
        int n = m0 + row;
        int swz = (row & 7) << 4;
        for (int k = g; k < 27; k += 4) {
            if (mk(mask, mflag, (size_t)n * 27 + k)) {
                int j = idx[(size_t)n * 27 + k];
                float f0 = feats[j * 3 + 0], f1 = feats[j * 3 + 1], f2 = feats[j * 3 + 2];
                int b0 = 2 * (3 * k + 0), b1 = b0 + 2, b2 = b0 + 4;
                *(unsigned short*)&A[row * 256 + (b0 ^ swz)] = f2bf(f0);
                *(unsigned short*)&A[row * 256 + (b1 ^ swz)] = f2bf(f1);
                *(unsigned short*)&A[row * 256 + (b2 ^ swz)] = f2bf(f2);
            }
        }
    }

    const char* wb = (const char*)win;
    f32x4 acc[4][4] = {};

    for (int ks = 0; ks < 2; ++ks) {
        __syncthreads();
        for (int i = 0; i < 8; ++i) {
            int chunk = wave * 8 + i;
            int o = chunk * 1024 + lane * 16;
            int corow = o >> 7;
            int inner = (o & 127) ^ ((corow & 7) << 4);
            gload16(wb + (size_t)corow * 256 + ks * 128 + inner, B + o);
        }
        __syncthreads();
        const int cw = wave * 64;
        for (int kk = 0; kk < 64; kk += 32) {
            int kl = kk + 8 * (lane >> 4);
            bf16x8 af[4], bfr[4];
            for (int mi = 0; mi < 4; ++mi) {
                int row = 16 * mi + (lane & 15);
                af[mi] = *(const bf16x8*)(A + row * 256 + ((ks * 128 + 2 * kl) ^ ((row & 7) << 4)));
            }
            for (int ni = 0; ni < 4; ++ni) {
                int corow = cw + 16 * ni + (lane & 15);
                bfr[ni] = *(const bf16x8*)(B + corow * 128 + ((2 * kl) ^ ((corow & 7) << 4)));
            }
            for (int mi = 0; mi < 4; ++mi)
                for (int ni = 0; ni < 4; ++ni)
                    acc[mi][ni] = __builtin_amdgcn_mfma_f32_16x16x32_bf16(af[mi], bfr[ni], acc[mi][ni], 0, 0, 0);
        }
    }

    const int cw = wave * 64;
    const int rq = 4 * (lane >> 4);
    const int colo = lane & 15;
    for (int mi = 0; mi < 4; ++mi)
        for (int ni = 0; ni < 4; ++ni) {
            int col = cw + 16 * ni + colo;
            for (int r = 0; r < 4; ++r) {
                float v = acc[mi][ni][r];
                float o = __shfl_xor(v, 1);
                if ((lane & 1) == 0) {
                    unsigned pk = (unsigned)f2bf(v) | ((unsigned)f2bf(o) << 16);
                    int row = m0 + 16 * mi + rq + r;
                    *(unsigned*)&yb[(size_t)row * CHID + col] = pk;
                }
            }
        }
}

// ---------------------------------------------------------------------------
// Conv GEMM: 256 rows x 256 co per block, 8 waves (2M x 4N, each 128x64),
// K=256 in 4 BK=64 steps, double-buffered 2-phase (stage(next) || compute(cur)).
// GATHER=false: self-offset, rows = blockIdx.x*256, pair-packed direct store.
// GATHER=true : k26 = blockIdx.x, tile = blockIdx.y (256 rows), pk-bf16 scatter.
// ---------------------------------------------------------------------------
template<bool GATHER>
__global__ __launch_bounds__(512, 1)
void conv_gemm(const unsigned short* __restrict__ hin,   // [N][256] bf16
               const unsigned short* __restrict__ Wp,    // [27][co=256][ci=256] bf16
               unsigned short* __restrict__ yb,          // [N][256] bf16
               const int* __restrict__ cnt,
               const int* __restrict__ srcL,
               const int* __restrict__ dstL) {
    // buffer b: A (256x64 bf16 swz) at b*65536, B (256x64 bf16 swz) at +32768
    __shared__ __align__(16) char lds[131072];
    __shared__ int ids_src[256];
    __shared__ int ids_dst[256];
    const int tid  = threadIdx.x;
    const int lane = tid & 63;
    const int wave = tid >> 6;
    const int wm = wave >> 2;       // 0..1  (row half)
    const int wn = wave & 3;        // 0..3  (col quarter)

    int k27, m0 = 0;
    if (GATHER) {
        int k26 = blockIdx.x;
        k27 = (k26 < 13) ? k26 : k26 + 1;
        int tile = blockIdx.y;
        int c = min(cnt[k26], CAP);
        if (tile * 256 >= c) return;
        if (tid < 256) {
            int g = tile * 256 + tid;
            bool v = (g < c);
            ids_src[tid] = v ? srcL[k26 * CAP + g] : 0;
            ids_dst[tid] = v ? dstL[k26 * CAP + g] : -1;
        }
        __syncthreads();
    } else {
        k27 = 13;
        m0 = blockIdx.x * 256;
    }
    const char* hbase = (const char*)hin;
    const char* wbase = (const char*)(Wp + (size_t)k27 * (CHID * CHID));

    f32x4 acc[8][4] = {};

    // stage one BK=64 K-step into buffer buf (A 32KB + B 32KB, 8 gload16/thread)
    auto STAGE = [&](int buf, int ks) {
        const int ci0 = ks * 64;
        char* dst = lds + buf * 65536;
        #pragma unroll
        for (int i = 0; i < 8; ++i) {
            int o = (wave * 8 + i) * 1024 + lane * 16;
            const char* src;
            if (o < 32768) {                       // A: waves 0..3 (uniform)
                int row = o >> 7;
                int inner = (o & 127) ^ ((row & 7) << 4);
                int grow = GATHER ? ids_src[row] : (m0 + row);
                src = hbase + (size_t)grow * 512 + ci0 * 2 + inner;
            } else {                               // B: waves 4..7
                int bo = o - 32768;
                int corow = bo >> 7;
                int inner = (bo & 127) ^ ((corow & 7) << 4);
                src = wbase + (size_t)corow * 512 + ci0 * 2 + inner;
            }
            gload16(src, dst + o);
        }
    };

    auto COMPUTE = [&](int buf) {
        const char* A = lds + buf * 65536;
        const char* B = A + 32768;
        #pragma unroll
        for (int kk = 0; kk < 64; kk += 32) {
            int kl = kk + 8 * (lane >> 4);
            bf16x8 af[8], bfr[4];
            #pragma unroll
            for (int mi = 0; mi < 8; ++mi) {
                int row = wm * 128 + 16 * mi + (lane & 15);
                af[mi] = *(const bf16x8*)(A + row * 128 + ((2 * kl) ^ ((row & 7) << 4)));
            }
            #pragma unroll
            for (int ni = 0; ni < 4; ++ni) {
                int corow = wn * 64 + 16 * ni + (lane & 15);
                bfr[ni] = *(const bf16x8*)(B + corow * 128 + ((2 * kl) ^ ((corow & 7) << 4)));
            }
            #pragma unroll
            for (int mi = 0; mi < 8; ++mi)
                #pragma unroll
                for (int ni = 0; ni < 4; ++ni)
                    acc[mi][ni] = __builtin_amdgcn_mfma_f32_16x16x32_bf16(af[mi], bfr[ni], acc[mi][ni], 0, 0, 0);
        }
    };

    // prologue
    STAGE(0, 0);
    __syncthreads();
    int cur = 0;
    #pragma unroll
    for (int ks = 0; ks < 4; ++ks) {
        if (ks < 3) STAGE(cur ^ 1, ks + 1);   // issue next-tile loads first
        COMPUTE(cur);                          // MFMA overlaps load flight
        __syncthreads();                       // compiler drains vmcnt+lgkmcnt
        cur ^= 1;
    }

    // epilogue: pair-packed bf16
    const int rq = 4 * (lane >> 4);
    const int colo = lane & 15;
    #pragma unroll
    for (int mi = 0; mi < 8; ++mi)
        #pragma unroll
        for (int ni = 0; ni < 4; ++ni) {
            int col = wn * 64 + 16 * ni + colo;
            #pragma unroll
            for (int r = 0; r < 4; ++r) {
                float v = acc[mi][ni][r];
                float o = __shfl_xor(v, 1);
                if ((lane & 1) == 0) {
                    unsigned pk = (unsigned)f2bf(v) | ((unsigned)f2bf(o) << 16);
                    int rl = wm * 128 + 16 * mi + rq + r;
                    if (!GATHER) {
                        *(unsigned*)&yb[(size_t)(m0 + rl) * CHID + col] = pk;
                    } else {
                        int dst = ids_dst[rl];
                        if (dst >= 0)
                            atomic_pk_bf16(&yb[(size_t)dst * CHID + col], pk);
                    }
                }
            }
        }
}

// ---------------------------------------------------------------------------
// BN stats on bf16 Y: per-channel sum & sumsq into st[0..255], st[256..511]
// ---------------------------------------------------------------------------
__global__ void bn_stats(const unsigned short* __restrict__ yb, float* __restrict__ st) {
    int t = threadIdx.x;
    int b = blockIdx.x;
    float s = 0.f, s2 = 0.f;
    size_t base = (size_t)b * 256 * CHID + t;
    for (int i = 0; i < 256; ++i) {
        float v = bf2f(yb[base + (size_t)i * CHID]);
        s += v; s2 += v * v;
    }
    unsafeAtomicAdd(&st[t], s);
    unsafeAtomicAdd(&st[256 + t], s2);
}

// ---------------------------------------------------------------------------
// BN apply (+optional residual) + ReLU -> bf16
// ---------------------------------------------------------------------------
__global__ void bn_apply(const unsigned short* __restrict__ yb, const float* __restrict__ st,
                         const float* __restrict__ g, const float* __restrict__ b,
                         const unsigned short* __restrict__ res, unsigned short* __restrict__ hout) {
    int t = threadIdx.x;
    float mean = st[t] * (1.f / NPTS);
    float var  = st[256 + t] * (1.f / NPTS) - mean * mean;
    float rstd = rsqrtf(var + 1e-5f);
    float sc = rstd * g[t];
    float bi = b[t] - mean * sc;
    size_t row0 = (size_t)blockIdx.x * 32;
    for (int i = 0; i < 32; ++i) {
        size_t off = (row0 + i) * CHID + t;
        float v = bf2f(yb[off]) * sc + bi;
        if (res) v += bf2f(res[off]);
        v = fmaxf(v, 0.f);
        hout[off] = f2bf(v);
    }
}

// ---------------------------------------------------------------------------
// Output GEMM: out[N][128] = h[N][256] @ w_out. 128x128 tile, 4 waves 2x2.
// ---------------------------------------------------------------------------
__global__ __launch_bounds__(256, 2)
void gemm_out(const unsigned short* __restrict__ hin, const unsigned short* __restrict__ wop,
              float* __restrict__ out) {
    __shared__ __align__(16) char lds[16384 + 16384];
    const int tid = threadIdx.x, lane = tid & 63, wave = tid >> 6;
    const int m0 = blockIdx.x * 128;
    const char* hb = (const char*)hin;
    const char* wb = (const char*)wop;
    f32x4 acc[4][4] = {};
    for (int ks = 0; ks < 4; ++ks) {
        int ci0 = ks * 64;
        __syncthreads();
        for (int i = 0; i < 8; ++i) {
            int chunk = wave * 8 + i;
            int o = chunk * 1024 + lane * 16;
            const char* src;
            if (o < 16384) {
                int row = o >> 7;
                int k2 = (o & 127) ^ ((row & 7) << 4);
                src = hb + (size_t)(m0 + row) * 512 + ci0 * 2 + k2;
            } else {
                int bo = o - 16384;
                int corow = bo >> 7;
                int k2 = (bo & 127) ^ ((corow & 7) << 4);
                src = wb + (size_t)corow * 512 + ci0 * 2 + k2;
            }
            gload16(src, lds + chunk * 1024);
        }
        __syncthreads();
        const char* A = lds;
        const char* B = lds + 16384;
        const int wm = wave >> 1, wn = wave & 1;
        for (int kk = 0; kk < 64; kk += 32) {
            int kl = kk + 8 * (lane >> 4);
            bf16x8 af[4], bfr[4];
            for (int mi = 0; mi < 4; ++mi) {
                int row = 64 * wm + 16 * mi + (lane & 15);
                af[mi] = *(const bf16x8*)(A + row * 128 + ((2 * kl) ^ ((row & 7) << 4)));
            }
            for (int ni = 0; ni < 4; ++ni) {
                int corow = 64 * wn + 16 * ni + (lane & 15);
                bfr[ni] = *(const bf16x8*)(B + corow * 128 + ((2 * kl) ^ ((corow & 7) << 4)));
            }
            for (int mi = 0; mi < 4; ++mi)
                for (int ni = 0; ni < 4; ++ni)
                    acc[mi][ni] = __builtin_amdgcn_mfma_f32_16x16x32_bf16(af[mi], bfr[ni], acc[mi][ni], 0, 0, 0);
        }
    }
    const int wm = wave >> 1, wn = wave & 1;
    for (int mi = 0; mi < 4; ++mi)
        for (int ni = 0; ni < 4; ++ni) {
            int col = 64 * wn + 16 * ni + (lane & 15);
            for (int r = 0; r < 4; ++r) {
                int row = m0 + 64 * wm + 16 * mi + 4 * (lane >> 4) + r;
                out[(size_t)row * 128 + col] = acc[mi][ni][r];
            }
        }
}

// ---------------------------------------------------------------------------
// Workspace layout (bytes)
// ---------------------------------------------------------------------------
static const size_t OFF_Y    = 0;                         // bf16 Y: 32 MiB
static const size_t OFF_HA   = OFF_Y   + (size_t)NPTS * CHID * 2;
static const size_t OFF_HR   = OFF_HA  + (size_t)NPTS * CHID * 2;
static const size_t OFF_WP   = OFF_HR  + (size_t)NPTS * CHID * 2;
static const size_t OFF_WOP  = OFF_WP  + (size_t)8 * 27 * 65536 * 2;
static const size_t OFF_WIN  = OFF_WOP + (size_t)128 * 256 * 2;
static const size_t OFF_ST   = OFF_WIN + (size_t)256 * 128 * 2;
static const size_t OFF_CNT  = OFF_ST  + 9 * 512 * 4;
static const size_t OFF_FLAG = OFF_CNT + 112;
static const size_t OFF_SRC  = OFF_CNT + 128;
static const size_t OFF_DST  = OFF_SRC + (size_t)26 * CAP * 4;
static const size_t OFF_BLK  = OFF_DST + (size_t)26 * CAP * 4;
static const size_t OFF_BAS  = OFF_BLK + (size_t)26 * LBLK * 4;

extern "C" void kernel_launch(void* const* d_in, const int* in_sizes, int n_in,
                              void* d_out, int out_size, void* d_ws, size_t ws_size,
                              hipStream_t stream) {
    const float* feats = (const float*)d_in[0];
    const float* w_in  = (const float*)d_in[1];
    const float* g_in  = (const float*)d_in[2];
    const float* b_in  = (const float*)d_in[3];
    const float* w_res = (const float*)d_in[4];
    const float* g_res = (const float*)d_in[5];
    const float* b_res = (const float*)d_in[6];
    const float* w_out = (const float*)d_in[7];
    const int*   nidx  = (const int*)d_in[8];
    const void*  nmask = (const void*)d_in[9];

    char* ws = (char*)d_ws;
    unsigned short* Yb   = (unsigned short*)(ws + OFF_Y);
    unsigned short* HA   = (unsigned short*)(ws + OFF_HA);
    unsigned short* HR   = (unsigned short*)(ws + OFF_HR);
    unsigned short* WP   = (unsigned short*)(ws + OFF_WP);
    unsigned short* WOP  = (unsigned short*)(ws + OFF_WOP);
    unsigned short* WIN  = (unsigned short*)(ws + OFF_WIN);
    float*          ST   = (float*)(ws + OFF_ST);
    int*            CNT  = (int*)(ws + OFF_CNT);
    int*            MFLG = (int*)(ws + OFF_FLAG);
    int*            SRCL = (int*)(ws + OFF_SRC);
    int*            DSTL = (int*)(ws + OFF_DST);
    int*            BLKC = (int*)(ws + OFF_BLK);
    int*            BASE = (int*)(ws + OFF_BAS);

    // zero BN stats (9 layers x 512 f32) + CNT slab + mask-dtype flag
    hipMemsetAsync(ws + OFF_ST, 0, 9 * 512 * 4 + 128, stream);

    detect_mask<<<64, 256, 0, stream>>>((const unsigned char*)nmask, MFLG);
    pack_w   <<<dim3(216, 16), 256, 0, stream>>>(w_res, WP);
    pack_wout<<<dim3(2, 4),    256, 0, stream>>>(w_out, WOP);
    pack_win <<<dim3(4, 2),    256, 0, stream>>>(w_in, WIN);

    count_lists<<<LBLK, 256, 0, stream>>>(nmask, MFLG, BLKC);
    scan_lists <<<1, 64, 0, stream>>>(BLKC, BASE, CNT);
    fill_lists <<<LBLK, 256, 0, stream>>>(nidx, nmask, MFLG, BASE, SRCL, DSTL);

    convin_gemm<<<NPTS / 64, 256, 0, stream>>>(feats, WIN, nidx, nmask, MFLG, Yb);
    bn_stats<<<256, 256, 0, stream>>>(Yb, ST);
    bn_apply<<<2048, 256, 0, stream>>>(Yb, ST, g_in, b_in, nullptr, HA);

    for (int c8 = 0; c8 < 8; ++c8) {
        const unsigned short* hin = (c8 & 1) ? HR : HA;
        const unsigned short* wbase = WP + (size_t)c8 * 27 * 65536;
        conv_gemm<false><<<NPTS / 256, 512, 0, stream>>>(hin, wbase, Yb, nullptr, nullptr, nullptr);
        conv_gemm<true><<<dim3(26, CAP / 256), 512, 0, stream>>>(hin, wbase, Yb, CNT, SRCL, DSTL);
        float* st = ST + (size_t)(1 + c8) * 512;
        bn_stats<<<256, 256, 0, stream>>>(Yb, st);
        if (c8 & 1) {
            bn_apply<<<2048, 256, 0, stream>>>(Yb, st, g_res + c8 * 256, b_res + c8 * 256, HA, HA);
        } else {
            bn_apply<<<2048, 256, 0, stream>>>(Yb, st, g_res + c8 * 256, b_res + c8 * 256, nullptr, HR);
        }
    }

    gemm_out<<<NPTS / 128, 256, 0, stream>>>(HA, WOP, (float*)d_out);
}

// Round 6
// 885.360 us; speedup vs baseline: 1.5625x; 1.0933x over previous
//
#include <hip/hip_runtime.h>
#include <hip/hip_bf16.h>

// ---------------------------------------------------------------------------
// Sparse 3D conv network (MinkowskiNet-ish) on MI355X.
//   y_self = h @ W[13]      (dense self-GEMM -> Y)
//   buf[e] = h[src(e)] @ W[k(e)]   (26 gather-GEMMs -> BUF, plain stores)
//   Y[n]  += sum over buf[nbr(n)]  (combine, fused with BN stats)
// then BN-apply(+residual)+ReLU -> bf16 h. NO scatter atomics anywhere.
// MFMA: v_mfma_f32_16x16x32_bf16, XOR-swizzled LDS, global_load_lds staging,
// 256x256 tile / BK=64 / 8 waves / double-buffered 2-phase K-loop.
// ---------------------------------------------------------------------------

#define NPTS 65536
#define CHID 256
#define CAP  4096   // per-offset list capacity (expected ~2030)
#define LBLK 256    // blocks in list-build phase (256 pts each)

typedef __bf16 bf16x8 __attribute__((ext_vector_type(8)));
typedef float  f32x4  __attribute__((ext_vector_type(4)));
typedef unsigned short u16x8 __attribute__((ext_vector_type(8)));

__device__ __forceinline__ float bf2f(unsigned short u) {
    union { float f; unsigned v; } x; x.v = ((unsigned)u) << 16; return x.f;
}
__device__ __forceinline__ unsigned short f2bf(float f) {
    union { float f; unsigned v; } x; x.f = f;
    unsigned r = x.v + 0x7fffu + ((x.v >> 16) & 1u);
    return (unsigned short)(r >> 16);
}

__device__ __forceinline__ void gload16(const void* g, void* l) {
    __builtin_amdgcn_global_load_lds(
        (const __attribute__((address_space(1))) void*)g,
        (__attribute__((address_space(3))) void*)l, 16, 0, 0);
}

// mask accessor: mflag==1 -> bool bytes, mflag==0 -> int32
__device__ __forceinline__ bool mk(const void* mask, int mflag, size_t i) {
    if (mflag) return ((const unsigned char*)mask)[i] != 0;
    return ((const int*)mask)[i] != 0;
}

// ---------------------------------------------------------------------------
// Detect mask dtype: any nonzero byte at offset %4!=0 => bool-bytes (flag=1).
// ---------------------------------------------------------------------------
__global__ void detect_mask(const unsigned char* __restrict__ m, int* __restrict__ flag) {
    int t = blockIdx.x * 256 + threadIdx.x;
    int any = 0;
    for (int i = t; i < 262144; i += 64 * 256)
        if ((i & 3) && m[i]) any = 1;
    if (any) atomicOr(flag, 1);
}

// ---------------------------------------------------------------------------
// Weight repack: w_res [8][27][ci=256][co=256] f32 -> [8][27][co=256][ci=256] bf16
// ---------------------------------------------------------------------------
__global__ void pack_w(const float* __restrict__ w, unsigned short* __restrict__ wp) {
    __shared__ float tile[64][65];
    int m   = blockIdx.x;
    int tci = (blockIdx.y >> 2) * 64;
    int tco = (blockIdx.y & 3) * 64;
    const float* src = w + (size_t)m * 65536;
    unsigned short* dst = wp + (size_t)m * 65536;
    int t = threadIdx.x, c = t & 63, rg = t >> 6;
    for (int r = rg; r < 64; r += 4)
        tile[r][c] = src[(size_t)(tci + r) * 256 + tco + c];
    __syncthreads();
    for (int r = rg; r < 64; r += 4)
        dst[(size_t)(tco + r) * 256 + tci + c] = f2bf(tile[c][r]);
}

// w_out [ci=256][co=128] f32 -> [co=128][ci=256] bf16
__global__ void pack_wout(const float* __restrict__ w, unsigned short* __restrict__ wp) {
    __shared__ float tile[64][65];
    int tco = blockIdx.x * 64, tci = blockIdx.y * 64;
    int t = threadIdx.x, c = t & 63, rg = t >> 6;
    for (int r = rg; r < 64; r += 4)
        tile[r][c] = w[(size_t)(tci + r) * 128 + tco + c];
    __syncthreads();
    for (int r = rg; r < 64; r += 4)
        wp[(size_t)(tco + r) * 256 + tci + c] = f2bf(tile[c][r]);
}

// w_in [27][3][256] == [81][256] f32 -> WIN [co=256][kk=128] bf16 (kk>=81 zero)
__global__ void pack_win(const float* __restrict__ w, unsigned short* __restrict__ wp) {
    __shared__ float tile[64][65];
    int cot = blockIdx.x * 64, kkt = blockIdx.y * 64;
    int t = threadIdx.x, c = t & 63, rg = t >> 6;
    for (int r = rg; r < 64; r += 4) {
        int kk = kkt + r;
        tile[r][c] = (kk < 81) ? w[(size_t)kk * 256 + cot + c] : 0.f;
    }
    __syncthreads();
    for (int r = rg; r < 64; r += 4)
        wp[(size_t)(cot + r) * 128 + kkt + c] = f2bf(tile[c][r]);
}

// ---------------------------------------------------------------------------
// Neighbor lists: deterministic 3-phase counting sort (no global atomics).
// fill also emits the inverse map: per point, entry ids of its contributions.
// ---------------------------------------------------------------------------
__global__ void count_lists(const void* __restrict__ mask, const int* __restrict__ mflagp,
                            int* __restrict__ blkcnt /*[26][LBLK]*/) {
    int mflag = *mflagp;
    int tid = threadIdx.x, lane = tid & 63;
    int n = blockIdx.x * 256 + tid;
    __shared__ int lc[26];
    if (tid < 26) lc[tid] = 0;
    __syncthreads();
    unsigned vb = 0;
    for (int k = 0; k < 27; ++k) {
        if (k == 13) continue;
        if (mk(mask, mflag, (size_t)n * 27 + k)) vb |= 1u << k;
    }
    for (int k26 = 0; k26 < 26; ++k26) {
        int k = (k26 < 13) ? k26 : k26 + 1;
        unsigned long long b = __ballot((vb >> k) & 1);
        if (lane == 0) atomicAdd(&lc[k26], __popcll(b));
    }
    __syncthreads();
    if (tid < 26) blkcnt[tid * LBLK + blockIdx.x] = lc[tid];
}

__global__ void scan_lists(const int* __restrict__ blkcnt, int* __restrict__ bases,
                           int* __restrict__ cnt) {
    int t = threadIdx.x;
    if (t < 26) {
        int s = 0;
        for (int b = 0; b < LBLK; ++b) {
            bases[t * LBLK + b] = s;
            s += blkcnt[t * LBLK + b];
        }
        cnt[t] = s;
    }
}

__global__ void fill_lists(const int* __restrict__ idx, const void* __restrict__ mask,
                           const int* __restrict__ mflagp, const int* __restrict__ bases,
                           int* __restrict__ srcL, int* __restrict__ nbrEnt,
                           unsigned char* __restrict__ nbrCnt) {
    int mflag = *mflagp;
    int tid = threadIdx.x, lane = tid & 63, wave = tid >> 6;
    int n = blockIdx.x * 256 + tid;
    __shared__ int wcnt[4][26];
    unsigned vb = 0;
    for (int k = 0; k < 27; ++k) {
        if (k == 13) continue;
        if (mk(mask, mflag, (size_t)n * 27 + k)) vb |= 1u << k;
    }
    for (int k26 = 0; k26 < 26; ++k26) {
        int k = (k26 < 13) ? k26 : k26 + 1;
        unsigned long long b = __ballot((vb >> k) & 1);
        if (lane == 0) wcnt[wave][k26] = __popcll(b);
    }
    __syncthreads();
    int j = 0;
    for (int k26 = 0; k26 < 26; ++k26) {
        int k = (k26 < 13) ? k26 : k26 + 1;
        bool v = (vb >> k) & 1;
        unsigned long long b = __ballot(v);
        if (v) {
            int p = bases[k26 * LBLK + blockIdx.x] + __popcll(b & ((1ull << lane) - 1ull));
            for (int w = 0; w < wave; ++w) p += wcnt[w][k26];
            if (p < CAP) {
                srcL[k26 * CAP + p] = idx[(size_t)n * 27 + k];
                nbrEnt[n * 32 + j] = k26 * CAP + p;
                ++j;
            }
        }
    }
    nbrCnt[n] = (unsigned char)j;
}

// ---------------------------------------------------------------------------
// Input conv as fused gather-GEMM: Y[64 rows][256 co] bf16 per block.
// ---------------------------------------------------------------------------
__global__ __launch_bounds__(256, 2)
void convin_gemm(const float* __restrict__ feats, const unsigned short* __restrict__ win,
                 const int* __restrict__ idx, const void* __restrict__ mask,
                 const int* __restrict__ mflagp, unsigned short* __restrict__ yb) {
    __shared__ __align__(16) char A[16384];   // 64 rows x 256 B (swizzled)
    __shared__ __align__(16) char B[32768];   // 256 co x 128 B per K-step
    const int mflag = *mflagp;
    const int tid = threadIdx.x, lane = tid & 63, wave = tid >> 6;
    const int m0 = blockIdx.x * 64;

    for (int i = 0; i < 4; ++i)
        *(f32x4*)&A[tid * 64 + i * 16] = f32x4{0.f, 0.f, 0.f, 0.f};
    __syncthreads();

    {
        int row = tid & 63, g = tid >> 6;
        int n = m0 + row;
        int swz = (row & 7) << 4;
        for (int k = g; k < 27; k += 4) {
            if (mk(mask, mflag, (size_t)n * 27 + k)) {
                int j = idx[(size_t)n * 27 + k];
                float f0 = feats[j * 3 + 0], f1 = feats[j * 3 + 1], f2 = feats[j * 3 + 2];
                int b0 = 2 * (3 * k + 0), b1 = b0 + 2, b2 = b0 + 4;
                *(unsigned short*)&A[row * 256 + (b0 ^ swz)] = f2bf(f0);
                *(unsigned short*)&A[row * 256 + (b1 ^ swz)] = f2bf(f1);
                *(unsigned short*)&A[row * 256 + (b2 ^ swz)] = f2bf(f2);
            }
        }
    }

    const char* wb = (const char*)win;
    f32x4 acc[4][4] = {};

    for (int ks = 0; ks < 2; ++ks) {
        __syncthreads();
        for (int i = 0; i < 8; ++i) {
            int chunk = wave * 8 + i;
            int o = chunk * 1024 + lane * 16;
            int corow = o >> 7;
            int inner = (o & 127) ^ ((corow & 7) << 4);
            gload16(wb + (size_t)corow * 256 + ks * 128 + inner, B + o);
        }
        __syncthreads();
        const int cw = wave * 64;
        for (int kk = 0; kk < 64; kk += 32) {
            int kl = kk + 8 * (lane >> 4);
            bf16x8 af[4], bfr[4];
            for (int mi = 0; mi < 4; ++mi) {
                int row = 16 * mi + (lane & 15);
                af[mi] = *(const bf16x8*)(A + row * 256 + ((ks * 128 + 2 * kl) ^ ((row & 7) << 4)));
            }
            for (int ni = 0; ni < 4; ++ni) {
                int corow = cw + 16 * ni + (lane & 15);
                bfr[ni] = *(const bf16x8*)(B + corow * 128 + ((2 * kl) ^ ((corow & 7) << 4)));
            }
            for (int mi = 0; mi < 4; ++mi)
                for (int ni = 0; ni < 4; ++ni)
                    acc[mi][ni] = __builtin_amdgcn_mfma_f32_16x16x32_bf16(af[mi], bfr[ni], acc[mi][ni], 0, 0, 0);
        }
    }

    const int cw = wave * 64;
    const int rq = 4 * (lane >> 4);
    const int colo = lane & 15;
    for (int mi = 0; mi < 4; ++mi)
        for (int ni = 0; ni < 4; ++ni) {
            int col = cw + 16 * ni + colo;
            for (int r = 0; r < 4; ++r) {
                float v = acc[mi][ni][r];
                float o = __shfl_xor(v, 1);
                if ((lane & 1) == 0) {
                    unsigned pk = (unsigned)f2bf(v) | ((unsigned)f2bf(o) << 16);
                    int row = m0 + 16 * mi + rq + r;
                    *(unsigned*)&yb[(size_t)row * CHID + col] = pk;
                }
            }
        }
}

// ---------------------------------------------------------------------------
// Conv GEMM: 256 rows x 256 co per block, 8 waves (2M x 4N), BK=64,
// double-buffered 2-phase. GATHER=false: self-offset -> Y direct store.
// GATHER=true: k26 = blockIdx.x, tile = blockIdx.y; output rows go to
// BUF[k26*CAP + g] with plain pair-packed stores (no atomics).
// ---------------------------------------------------------------------------
template<bool GATHER>
__global__ __launch_bounds__(512, 1)
void conv_gemm(const unsigned short* __restrict__ hin,   // [N][256] bf16
               const unsigned short* __restrict__ Wp,    // [27][co=256][ci=256] bf16
               unsigned short* __restrict__ yb,          // Y (self) or BUF (gather)
               const int* __restrict__ cnt,
               const int* __restrict__ srcL) {
    __shared__ __align__(16) char lds[131072];
    __shared__ int ids_src[256];
    const int tid  = threadIdx.x;
    const int lane = tid & 63;
    const int wave = tid >> 6;
    const int wm = wave >> 2;       // 0..1  (row half)
    const int wn = wave & 3;        // 0..3  (col quarter)

    int k27 = 13, m0 = 0, k26 = 0, tile = 0, c = 0;
    if (GATHER) {
        k26 = blockIdx.x;
        k27 = (k26 < 13) ? k26 : k26 + 1;
        tile = blockIdx.y;
        c = min(cnt[k26], CAP);
        if (tile * 256 >= c) return;
        if (tid < 256) {
            int g = tile * 256 + tid;
            ids_src[tid] = (g < c) ? srcL[k26 * CAP + g] : 0;
        }
        __syncthreads();
    } else {
        m0 = blockIdx.x * 256;
    }
    const char* hbase = (const char*)hin;
    const char* wbase = (const char*)(Wp + (size_t)k27 * (CHID * CHID));

    f32x4 acc[8][4] = {};

    auto STAGE = [&](int buf, int ks) {
        const int ci0 = ks * 64;
        char* dst = lds + buf * 65536;
        #pragma unroll
        for (int i = 0; i < 8; ++i) {
            int o = (wave * 8 + i) * 1024 + lane * 16;
            const char* src;
            if (o < 32768) {                       // A: waves 0..3
                int row = o >> 7;
                int inner = (o & 127) ^ ((row & 7) << 4);
                int grow = GATHER ? ids_src[row] : (m0 + row);
                src = hbase + (size_t)grow * 512 + ci0 * 2 + inner;
            } else {                               // B: waves 4..7
                int bo = o - 32768;
                int corow = bo >> 7;
                int inner = (bo & 127) ^ ((corow & 7) << 4);
                src = wbase + (size_t)corow * 512 + ci0 * 2 + inner;
            }
            gload16(src, dst + o);
        }
    };

    auto COMPUTE = [&](int buf) {
        const char* A = lds + buf * 65536;
        const char* B = A + 32768;
        #pragma unroll
        for (int kk = 0; kk < 64; kk += 32) {
            int kl = kk + 8 * (lane >> 4);
            bf16x8 af[8], bfr[4];
            #pragma unroll
            for (int mi = 0; mi < 8; ++mi) {
                int row = wm * 128 + 16 * mi + (lane & 15);
                af[mi] = *(const bf16x8*)(A + row * 128 + ((2 * kl) ^ ((row & 7) << 4)));
            }
            #pragma unroll
            for (int ni = 0; ni < 4; ++ni) {
                int corow = wn * 64 + 16 * ni + (lane & 15);
                bfr[ni] = *(const bf16x8*)(B + corow * 128 + ((2 * kl) ^ ((corow & 7) << 4)));
            }
            #pragma unroll
            for (int mi = 0; mi < 8; ++mi)
                #pragma unroll
                for (int ni = 0; ni < 4; ++ni)
                    acc[mi][ni] = __builtin_amdgcn_mfma_f32_16x16x32_bf16(af[mi], bfr[ni], acc[mi][ni], 0, 0, 0);
        }
    };

    STAGE(0, 0);
    __syncthreads();
    int cur = 0;
    #pragma unroll
    for (int ks = 0; ks < 4; ++ks) {
        if (ks < 3) STAGE(cur ^ 1, ks + 1);   // issue next-tile loads first
        COMPUTE(cur);                          // MFMA overlaps load flight
        __syncthreads();
        cur ^= 1;
    }

    // epilogue: pair-packed bf16 plain stores
    const int rq = 4 * (lane >> 4);
    const int colo = lane & 15;
    #pragma unroll
    for (int mi = 0; mi < 8; ++mi)
        #pragma unroll
        for (int ni = 0; ni < 4; ++ni) {
            int col = wn * 64 + 16 * ni + colo;
            #pragma unroll
            for (int r = 0; r < 4; ++r) {
                float v = acc[mi][ni][r];
                float o = __shfl_xor(v, 1);
                if ((lane & 1) == 0) {
                    unsigned pk = (unsigned)f2bf(v) | ((unsigned)f2bf(o) << 16);
                    int rl = wm * 128 + 16 * mi + rq + r;
                    if (!GATHER) {
                        *(unsigned*)&yb[(size_t)(m0 + rl) * CHID + col] = pk;
                    } else {
                        int g = tile * 256 + rl;
                        if (g < c)
                            *(unsigned*)&yb[((size_t)k26 * CAP + g) * CHID + col] = pk;
                    }
                }
            }
        }
}

// ---------------------------------------------------------------------------
// Combine + BN stats: Y[n] += sum_j buf[nbrEnt[n][j]]; write Y; accumulate
// per-channel sum/sumsq (LDS-reduced, then 512 global atomics per block).
// Grid: 512 blocks x 128 rows. Thread t: row-slot t>>5, col octet (t&31)*8.
// ---------------------------------------------------------------------------
__global__ __launch_bounds__(256)
void combine_stats(unsigned short* __restrict__ Yb,
                   const unsigned short* __restrict__ buf,
                   const int* __restrict__ nbrEnt,
                   const unsigned char* __restrict__ nbrCnt,
                   float* __restrict__ st) {
    __shared__ float ssum[8][256];
    __shared__ float ssq[8][256];
    const int tid = threadIdx.x;
    const int grp = tid >> 5;
    const int c0  = (tid & 31) * 8;
    float s[8] = {}, s2[8] = {};
    const int row0 = blockIdx.x * 128;
    for (int it = 0; it < 16; ++it) {
        int row = row0 + it * 8 + grp;
        size_t off = (size_t)row * CHID + c0;
        u16x8 y = *(const u16x8*)&Yb[off];
        float v[8];
        #pragma unroll
        for (int q = 0; q < 8; ++q) v[q] = bf2f(y[q]);
        int cnt = nbrCnt[row];
        for (int j = 0; j < cnt; ++j) {
            int e = nbrEnt[row * 32 + j];
            u16x8 b = *(const u16x8*)&buf[(size_t)e * CHID + c0];
            #pragma unroll
            for (int q = 0; q < 8; ++q) v[q] += bf2f(b[q]);
        }
        u16x8 o;
        #pragma unroll
        for (int q = 0; q < 8; ++q) {
            o[q] = f2bf(v[q]);
            s[q] += v[q];
            s2[q] += v[q] * v[q];
        }
        *(u16x8*)&Yb[off] = o;
    }
    #pragma unroll
    for (int q = 0; q < 8; ++q) {
        ssum[grp][c0 + q] = s[q];
        ssq[grp][c0 + q]  = s2[q];
    }
    __syncthreads();
    // thread t owns channel t: reduce the 8 row-groups
    float ts = 0.f, tq = 0.f;
    #pragma unroll
    for (int g = 0; g < 8; ++g) { ts += ssum[g][tid]; tq += ssq[g][tid]; }
    unsafeAtomicAdd(&st[tid], ts);
    unsafeAtomicAdd(&st[256 + tid], tq);
}

// ---------------------------------------------------------------------------
// BN stats (layer 0 only) on bf16 Y
// ---------------------------------------------------------------------------
__global__ void bn_stats(const unsigned short* __restrict__ yb, float* __restrict__ st) {
    int t = threadIdx.x;
    int b = blockIdx.x;
    float s = 0.f, s2 = 0.f;
    size_t base = (size_t)b * 256 * CHID + t;
    for (int i = 0; i < 256; ++i) {
        float v = bf2f(yb[base + (size_t)i * CHID]);
        s += v; s2 += v * v;
    }
    unsafeAtomicAdd(&st[t], s);
    unsafeAtomicAdd(&st[256 + t], s2);
}

// ---------------------------------------------------------------------------
// BN apply (+optional residual) + ReLU -> bf16
// ---------------------------------------------------------------------------
__global__ void bn_apply(const unsigned short* __restrict__ yb, const float* __restrict__ st,
                         const float* __restrict__ g, const float* __restrict__ b,
                         const unsigned short* __restrict__ res, unsigned short* __restrict__ hout) {
    int t = threadIdx.x;
    float mean = st[t] * (1.f / NPTS);
    float var  = st[256 + t] * (1.f / NPTS) - mean * mean;
    float rstd = rsqrtf(var + 1e-5f);
    float sc = rstd * g[t];
    float bi = b[t] - mean * sc;
    size_t row0 = (size_t)blockIdx.x * 32;
    for (int i = 0; i < 32; ++i) {
        size_t off = (row0 + i) * CHID + t;
        float v = bf2f(yb[off]) * sc + bi;
        if (res) v += bf2f(res[off]);
        v = fmaxf(v, 0.f);
        hout[off] = f2bf(v);
    }
}

// ---------------------------------------------------------------------------
// Output GEMM: out[N][128] = h[N][256] @ w_out. 128x128 tile, 4 waves 2x2.
// ---------------------------------------------------------------------------
__global__ __launch_bounds__(256, 2)
void gemm_out(const unsigned short* __restrict__ hin, const unsigned short* __restrict__ wop,
              float* __restrict__ out) {
    __shared__ __align__(16) char lds[16384 + 16384];
    const int tid = threadIdx.x, lane = tid & 63, wave = tid >> 6;
    const int m0 = blockIdx.x * 128;
    const char* hb = (const char*)hin;
    const char* wb = (const char*)wop;
    f32x4 acc[4][4] = {};
    for (int ks = 0; ks < 4; ++ks) {
        int ci0 = ks * 64;
        __syncthreads();
        for (int i = 0; i < 8; ++i) {
            int chunk = wave * 8 + i;
            int o = chunk * 1024 + lane * 16;
            const char* src;
            if (o < 16384) {
                int row = o >> 7;
                int k2 = (o & 127) ^ ((row & 7) << 4);
                src = hb + (size_t)(m0 + row) * 512 + ci0 * 2 + k2;
            } else {
                int bo = o - 16384;
                int corow = bo >> 7;
                int k2 = (bo & 127) ^ ((corow & 7) << 4);
                src = wb + (size_t)corow * 512 + ci0 * 2 + k2;
            }
            gload16(src, lds + chunk * 1024);
        }
        __syncthreads();
        const char* A = lds;
        const char* B = lds + 16384;
        const int wm = wave >> 1, wn = wave & 1;
        for (int kk = 0; kk < 64; kk += 32) {
            int kl = kk + 8 * (lane >> 4);
            bf16x8 af[4], bfr[4];
            for (int mi = 0; mi < 4; ++mi) {
                int row = 64 * wm + 16 * mi + (lane & 15);
                af[mi] = *(const bf16x8*)(A + row * 128 + ((2 * kl) ^ ((row & 7) << 4)));
            }
            for (int ni = 0; ni < 4; ++ni) {
                int corow = 64 * wn + 16 * ni + (lane & 15);
                bfr[ni] = *(const bf16x8*)(B + corow * 128 + ((2 * kl) ^ ((corow & 7) << 4)));
            }
            for (int mi = 0; mi < 4; ++mi)
                for (int ni = 0; ni < 4; ++ni)
                    acc[mi][ni] = __builtin_amdgcn_mfma_f32_16x16x32_bf16(af[mi], bfr[ni], acc[mi][ni], 0, 0, 0);
        }
    }
    const int wm = wave >> 1, wn = wave & 1;
    for (int mi = 0; mi < 4; ++mi)
        for (int ni = 0; ni < 4; ++ni) {
            int col = 64 * wn + 16 * ni + (lane & 15);
            for (int r = 0; r < 4; ++r) {
                int row = m0 + 64 * wm + 16 * mi + 4 * (lane >> 4) + r;
                out[(size_t)row * 128 + col] = acc[mi][ni][r];
            }
        }
}

// ---------------------------------------------------------------------------
// Workspace layout (bytes); total ~184 MiB
// ---------------------------------------------------------------------------
static const size_t OFF_Y    = 0;                         // bf16 Y: 33.5 MB
static const size_t OFF_HA   = OFF_Y   + (size_t)NPTS * CHID * 2;
static const size_t OFF_HR   = OFF_HA  + (size_t)NPTS * CHID * 2;
static const size_t OFF_WP   = OFF_HR  + (size_t)NPTS * CHID * 2;
static const size_t OFF_WOP  = OFF_WP  + (size_t)8 * 27 * 65536 * 2;
static const size_t OFF_WIN  = OFF_WOP + (size_t)128 * 256 * 2;
static const size_t OFF_ST   = OFF_WIN + (size_t)256 * 128 * 2;
static const size_t OFF_CNT  = OFF_ST  + 9 * 512 * 4;
static const size_t OFF_FLAG = OFF_CNT + 112;
static const size_t OFF_SRC  = OFF_CNT + 128;
static const size_t OFF_BLK  = OFF_SRC + (size_t)26 * CAP * 4;
static const size_t OFF_BAS  = OFF_BLK + (size_t)26 * LBLK * 4;
static const size_t OFF_NBE  = OFF_BAS + (size_t)26 * LBLK * 4;   // [N][32] int
static const size_t OFF_NBC  = OFF_NBE + (size_t)NPTS * 32 * 4;   // [N] u8
static const size_t OFF_BUF  = OFF_NBC + (size_t)NPTS;            // [26*CAP][256] bf16

extern "C" void kernel_launch(void* const* d_in, const int* in_sizes, int n_in,
                              void* d_out, int out_size, void* d_ws, size_t ws_size,
                              hipStream_t stream) {
    const float* feats = (const float*)d_in[0];
    const float* w_in  = (const float*)d_in[1];
    const float* g_in  = (const float*)d_in[2];
    const float* b_in  = (const float*)d_in[3];
    const float* w_res = (const float*)d_in[4];
    const float* g_res = (const float*)d_in[5];
    const float* b_res = (const float*)d_in[6];
    const float* w_out = (const float*)d_in[7];
    const int*   nidx  = (const int*)d_in[8];
    const void*  nmask = (const void*)d_in[9];

    char* ws = (char*)d_ws;
    unsigned short* Yb   = (unsigned short*)(ws + OFF_Y);
    unsigned short* HA   = (unsigned short*)(ws + OFF_HA);
    unsigned short* HR   = (unsigned short*)(ws + OFF_HR);
    unsigned short* WP   = (unsigned short*)(ws + OFF_WP);
    unsigned short* WOP  = (unsigned short*)(ws + OFF_WOP);
    unsigned short* WIN  = (unsigned short*)(ws + OFF_WIN);
    float*          ST   = (float*)(ws + OFF_ST);
    int*            CNT  = (int*)(ws + OFF_CNT);
    int*            MFLG = (int*)(ws + OFF_FLAG);
    int*            SRCL = (int*)(ws + OFF_SRC);
    int*            BLKC = (int*)(ws + OFF_BLK);
    int*            BASE = (int*)(ws + OFF_BAS);
    int*            NBE  = (int*)(ws + OFF_NBE);
    unsigned char*  NBC  = (unsigned char*)(ws + OFF_NBC);
    unsigned short* BUF  = (unsigned short*)(ws + OFF_BUF);

    // zero BN stats (9 layers x 512 f32) + CNT slab + mask-dtype flag
    hipMemsetAsync(ws + OFF_ST, 0, 9 * 512 * 4 + 128, stream);

    detect_mask<<<64, 256, 0, stream>>>((const unsigned char*)nmask, MFLG);
    pack_w   <<<dim3(216, 16), 256, 0, stream>>>(w_res, WP);
    pack_wout<<<dim3(2, 4),    256, 0, stream>>>(w_out, WOP);
    pack_win <<<dim3(4, 2),    256, 0, stream>>>(w_in, WIN);

    count_lists<<<LBLK, 256, 0, stream>>>(nmask, MFLG, BLKC);
    scan_lists <<<1, 64, 0, stream>>>(BLKC, BASE, CNT);
    fill_lists <<<LBLK, 256, 0, stream>>>(nidx, nmask, MFLG, BASE, SRCL, NBE, NBC);

    convin_gemm<<<NPTS / 64, 256, 0, stream>>>(feats, WIN, nidx, nmask, MFLG, Yb);
    bn_stats<<<256, 256, 0, stream>>>(Yb, ST);
    bn_apply<<<2048, 256, 0, stream>>>(Yb, ST, g_in, b_in, nullptr, HA);

    for (int c8 = 0; c8 < 8; ++c8) {
        const unsigned short* hin = (c8 & 1) ? HR : HA;
        const unsigned short* wbase = WP + (size_t)c8 * 27 * 65536;
        float* st = ST + (size_t)(1 + c8) * 512;
        conv_gemm<false><<<NPTS / 256, 512, 0, stream>>>(hin, wbase, Yb, nullptr, nullptr);
        conv_gemm<true><<<dim3(26, CAP / 256), 512, 0, stream>>>(hin, wbase, BUF, CNT, SRCL);
        combine_stats<<<512, 256, 0, stream>>>(Yb, BUF, NBE, NBC, st);
        if (c8 & 1) {
            bn_apply<<<2048, 256, 0, stream>>>(Yb, st, g_res + c8 * 256, b_res + c8 * 256, HA, HA);
        } else {
            bn_apply<<<2048, 256, 0, stream>>>(Yb, st, g_res + c8 * 256, b_res + c8 * 256, nullptr, HR);
        }
    }

    gemm_out<<<NPTS / 128, 256, 0, stream>>>(HA, WOP, (float*)d_out);
}

// Round 7
// 788.042 us; speedup vs baseline: 1.7554x; 1.1235x over previous
//
#include <hip/hip_runtime.h>
#include <hip/hip_bf16.h>

// ---------------------------------------------------------------------------
// Sparse 3D conv network (MinkowskiNet-ish) on MI355X.
//   y_self = h @ W[13]      (dense self-GEMM -> Y)
//   buf[e] = h[src(e)] @ W[k(e)]   (26 gather-GEMMs -> BUF, plain stores)
//   Y[n]  += sum over buf[nbr(n)]  (combine, fused with BN partial stats)
// then reduce_stats + BN-apply(+residual)+ReLU -> bf16 h. No scatter atomics.
// MFMA: v_mfma_f32_16x16x32_bf16, XOR-swizzled LDS, global_load_lds staging,
// 256x256 tile / BK=64 / 8 waves / double-buffered 2-phase K-loop.
// ---------------------------------------------------------------------------

#define NPTS 65536
#define CHID 256
#define CAP  4096   // per-offset list capacity (expected ~2030)
#define LBLK 256    // blocks in list-build phase (256 pts each)
#define CBLK 2048   // blocks in combine/apply phase (32 rows each)

typedef __bf16 bf16x8 __attribute__((ext_vector_type(8)));
typedef float  f32x4  __attribute__((ext_vector_type(4)));
typedef unsigned short u16x8 __attribute__((ext_vector_type(8)));

__device__ __forceinline__ float bf2f(unsigned short u) {
    union { float f; unsigned v; } x; x.v = ((unsigned)u) << 16; return x.f;
}
__device__ __forceinline__ unsigned short f2bf(float f) {
    union { float f; unsigned v; } x; x.f = f;
    unsigned r = x.v + 0x7fffu + ((x.v >> 16) & 1u);
    return (unsigned short)(r >> 16);
}

__device__ __forceinline__ void gload16(const void* g, void* l) {
    __builtin_amdgcn_global_load_lds(
        (const __attribute__((address_space(1))) void*)g,
        (__attribute__((address_space(3))) void*)l, 16, 0, 0);
}

// mask accessor: mflag==1 -> bool bytes, mflag==0 -> int32
__device__ __forceinline__ bool mk(const void* mask, int mflag, size_t i) {
    if (mflag) return ((const unsigned char*)mask)[i] != 0;
    return ((const int*)mask)[i] != 0;
}

// ---------------------------------------------------------------------------
// Detect mask dtype: any nonzero byte at offset %4!=0 => bool-bytes (flag=1).
// ---------------------------------------------------------------------------
__global__ void detect_mask(const unsigned char* __restrict__ m, int* __restrict__ flag) {
    int t = blockIdx.x * 256 + threadIdx.x;
    int any = 0;
    for (int i = t; i < 262144; i += 64 * 256)
        if ((i & 3) && m[i]) any = 1;
    if (any) atomicOr(flag, 1);
}

// ---------------------------------------------------------------------------
// Weight repack: w_res [8][27][ci=256][co=256] f32 -> [8][27][co=256][ci=256] bf16
// ---------------------------------------------------------------------------
__global__ void pack_w(const float* __restrict__ w, unsigned short* __restrict__ wp) {
    __shared__ float tile[64][65];
    int m   = blockIdx.x;
    int tci = (blockIdx.y >> 2) * 64;
    int tco = (blockIdx.y & 3) * 64;
    const float* src = w + (size_t)m * 65536;
    unsigned short* dst = wp + (size_t)m * 65536;
    int t = threadIdx.x, c = t & 63, rg = t >> 6;
    for (int r = rg; r < 64; r += 4)
        tile[r][c] = src[(size_t)(tci + r) * 256 + tco + c];
    __syncthreads();
    for (int r = rg; r < 64; r += 4)
        dst[(size_t)(tco + r) * 256 + tci + c] = f2bf(tile[c][r]);
}

// w_out [ci=256][co=128] f32 -> [co=128][ci=256] bf16
__global__ void pack_wout(const float* __restrict__ w, unsigned short* __restrict__ wp) {
    __shared__ float tile[64][65];
    int tco = blockIdx.x * 64, tci = blockIdx.y * 64;
    int t = threadIdx.x, c = t & 63, rg = t >> 6;
    for (int r = rg; r < 64; r += 4)
        tile[r][c] = w[(size_t)(tci + r) * 128 + tco + c];
    __syncthreads();
    for (int r = rg; r < 64; r += 4)
        wp[(size_t)(tco + r) * 256 + tci + c] = f2bf(tile[c][r]);
}

// w_in [27][3][256] == [81][256] f32 -> WIN [co=256][kk=128] bf16 (kk>=81 zero)
__global__ void pack_win(const float* __restrict__ w, unsigned short* __restrict__ wp) {
    __shared__ float tile[64][65];
    int cot = blockIdx.x * 64, kkt = blockIdx.y * 64;
    int t = threadIdx.x, c = t & 63, rg = t >> 6;
    for (int r = rg; r < 64; r += 4) {
        int kk = kkt + r;
        tile[r][c] = (kk < 81) ? w[(size_t)kk * 256 + cot + c] : 0.f;
    }
    __syncthreads();
    for (int r = rg; r < 64; r += 4)
        wp[(size_t)(cot + r) * 128 + kkt + c] = f2bf(tile[c][r]);
}

// ---------------------------------------------------------------------------
// Neighbor lists: deterministic 3-phase counting sort (no global atomics).
// fill also emits the inverse map: per point, entry ids of its contributions.
// ---------------------------------------------------------------------------
__global__ void count_lists(const void* __restrict__ mask, const int* __restrict__ mflagp,
                            int* __restrict__ blkcnt /*[26][LBLK]*/) {
    int mflag = *mflagp;
    int tid = threadIdx.x, lane = tid & 63;
    int n = blockIdx.x * 256 + tid;
    __shared__ int lc[26];
    if (tid < 26) lc[tid] = 0;
    __syncthreads();
    unsigned vb = 0;
    for (int k = 0; k < 27; ++k) {
        if (k == 13) continue;
        if (mk(mask, mflag, (size_t)n * 27 + k)) vb |= 1u << k;
    }
    for (int k26 = 0; k26 < 26; ++k26) {
        int k = (k26 < 13) ? k26 : k26 + 1;
        unsigned long long b = __ballot((vb >> k) & 1);
        if (lane == 0) atomicAdd(&lc[k26], __popcll(b));
    }
    __syncthreads();
    if (tid < 26) blkcnt[tid * LBLK + blockIdx.x] = lc[tid];
}

__global__ void scan_lists(const int* __restrict__ blkcnt, int* __restrict__ bases,
                           int* __restrict__ cnt) {
    int t = threadIdx.x;
    if (t < 26) {
        int s = 0;
        for (int b = 0; b < LBLK; ++b) {
            bases[t * LBLK + b] = s;
            s += blkcnt[t * LBLK + b];
        }
        cnt[t] = s;
    }
}

__global__ void fill_lists(const int* __restrict__ idx, const void* __restrict__ mask,
                           const int* __restrict__ mflagp, const int* __restrict__ bases,
                           int* __restrict__ srcL, int* __restrict__ nbrEnt,
                           unsigned char* __restrict__ nbrCnt) {
    int mflag = *mflagp;
    int tid = threadIdx.x, lane = tid & 63, wave = tid >> 6;
    int n = blockIdx.x * 256 + tid;
    __shared__ int wcnt[4][26];
    unsigned vb = 0;
    for (int k = 0; k < 27; ++k) {
        if (k == 13) continue;
        if (mk(mask, mflag, (size_t)n * 27 + k)) vb |= 1u << k;
    }
    for (int k26 = 0; k26 < 26; ++k26) {
        int k = (k26 < 13) ? k26 : k26 + 1;
        unsigned long long b = __ballot((vb >> k) & 1);
        if (lane == 0) wcnt[wave][k26] = __popcll(b);
    }
    __syncthreads();
    int j = 0;
    for (int k26 = 0; k26 < 26; ++k26) {
        int k = (k26 < 13) ? k26 : k26 + 1;
        bool v = (vb >> k) & 1;
        unsigned long long b = __ballot(v);
        if (v) {
            int p = bases[k26 * LBLK + blockIdx.x] + __popcll(b & ((1ull << lane) - 1ull));
            for (int w = 0; w < wave; ++w) p += wcnt[w][k26];
            if (p < CAP) {
                srcL[k26 * CAP + p] = idx[(size_t)n * 27 + k];
                nbrEnt[n * 32 + j] = k26 * CAP + p;
                ++j;
            }
        }
    }
    nbrCnt[n] = (unsigned char)j;
}

// ---------------------------------------------------------------------------
// Input conv as fused gather-GEMM: Y[64 rows][256 co] bf16 per block.
// ---------------------------------------------------------------------------
__global__ __launch_bounds__(256, 2)
void convin_gemm(const float* __restrict__ feats, const unsigned short* __restrict__ win,
                 const int* __restrict__ idx, const void* __restrict__ mask,
                 const int* __restrict__ mflagp, unsigned short* __restrict__ yb) {
    __shared__ __align__(16) char A[16384];   // 64 rows x 256 B (swizzled)
    __shared__ __align__(16) char B[32768];   // 256 co x 128 B per K-step
    const int mflag = *mflagp;
    const int tid = threadIdx.x, lane = tid & 63, wave = tid >> 6;
    const int m0 = blockIdx.x * 64;

    for (int i = 0; i < 4; ++i)
        *(f32x4*)&A[tid * 64 + i * 16] = f32x4{0.f, 0.f, 0.f, 0.f};
    __syncthreads();

    {
        int row = tid & 63, g = tid >> 6;
        int n = m0 + row;
        int swz = (row & 7) << 4;
        for (int k = g; k < 27; k += 4) {
            if (mk(mask, mflag, (size_t)n * 27 + k)) {
                int j = idx[(size_t)n * 27 + k];
                float f0 = feats[j * 3 + 0], f1 = feats[j * 3 + 1], f2 = feats[j * 3 + 2];
                int b0 = 2 * (3 * k + 0), b1 = b0 + 2, b2 = b0 + 4;
                *(unsigned short*)&A[row * 256 + (b0 ^ swz)] = f2bf(f0);
                *(unsigned short*)&A[row * 256 + (b1 ^ swz)] = f2bf(f1);
                *(unsigned short*)&A[row * 256 + (b2 ^ swz)] = f2bf(f2);
            }
        }
    }

    const char* wb = (const char*)win;
    f32x4 acc[4][4] = {};

    for (int ks = 0; ks < 2; ++ks) {
        __syncthreads();
        for (int i = 0; i < 8; ++i) {
            int chunk = wave * 8 + i;
            int o = chunk * 1024 + lane * 16;
            int corow = o >> 7;
            int inner = (o & 127) ^ ((corow & 7) << 4);
            gload16(wb + (size_t)corow * 256 + ks * 128 + inner, B + o);
        }
        __syncthreads();
        const int cw = wave * 64;
        for (int kk = 0; kk < 64; kk += 32) {
            int kl = kk + 8 * (lane >> 4);
            bf16x8 af[4], bfr[4];
            for (int mi = 0; mi < 4; ++mi) {
                int row = 16 * mi + (lane & 15);
                af[mi] = *(const bf16x8*)(A + row * 256 + ((ks * 128 + 2 * kl) ^ ((row & 7) << 4)));
            }
            for (int ni = 0; ni < 4; ++ni) {
                int corow = cw + 16 * ni + (lane & 15);
                bfr[ni] = *(const bf16x8*)(B + corow * 128 + ((2 * kl) ^ ((corow & 7) << 4)));
            }
            for (int mi = 0; mi < 4; ++mi)
                for (int ni = 0; ni < 4; ++ni)
                    acc[mi][ni] = __builtin_amdgcn_mfma_f32_16x16x32_bf16(af[mi], bfr[ni], acc[mi][ni], 0, 0, 0);
        }
    }

    const int cw = wave * 64;
    const int rq = 4 * (lane >> 4);
    const int colo = lane & 15;
    for (int mi = 0; mi < 4; ++mi)
        for (int ni = 0; ni < 4; ++ni) {
            int col = cw + 16 * ni + colo;
            for (int r = 0; r < 4; ++r) {
                float v = acc[mi][ni][r];
                float o = __shfl_xor(v, 1);
                if ((lane & 1) == 0) {
                    unsigned pk = (unsigned)f2bf(v) | ((unsigned)f2bf(o) << 16);
                    int row = m0 + 16 * mi + rq + r;
                    *(unsigned*)&yb[(size_t)row * CHID + col] = pk;
                }
            }
        }
}

// ---------------------------------------------------------------------------
// Conv GEMM: 256 rows x 256 co per block, 8 waves (2M x 4N), BK=64,
// double-buffered 2-phase. GATHER=false: self-offset -> Y direct store.
// GATHER=true: k26 = blockIdx.x, tile = blockIdx.y; output rows go to
// BUF[k26*CAP + g] with plain pair-packed stores (no atomics).
// ---------------------------------------------------------------------------
template<bool GATHER>
__global__ __launch_bounds__(512, 1)
void conv_gemm(const unsigned short* __restrict__ hin,   // [N][256] bf16
               const unsigned short* __restrict__ Wp,    // [27][co=256][ci=256] bf16
               unsigned short* __restrict__ yb,          // Y (self) or BUF (gather)
               const int* __restrict__ cnt,
               const int* __restrict__ srcL) {
    __shared__ __align__(16) char lds[131072];
    __shared__ int ids_src[256];
    const int tid  = threadIdx.x;
    const int lane = tid & 63;
    const int wave = tid >> 6;
    const int wm = wave >> 2;       // 0..1  (row half)
    const int wn = wave & 3;        // 0..3  (col quarter)

    int k27 = 13, m0 = 0, k26 = 0, tile = 0, c = 0;
    if (GATHER) {
        k26 = blockIdx.x;
        k27 = (k26 < 13) ? k26 : k26 + 1;
        tile = blockIdx.y;
        c = min(cnt[k26], CAP);
        if (tile * 256 >= c) return;
        if (tid < 256) {
            int g = tile * 256 + tid;
            ids_src[tid] = (g < c) ? srcL[k26 * CAP + g] : 0;
        }
        __syncthreads();
    } else {
        m0 = blockIdx.x * 256;
    }
    const char* hbase = (const char*)hin;
    const char* wbase = (const char*)(Wp + (size_t)k27 * (CHID * CHID));

    f32x4 acc[8][4] = {};

    auto STAGE = [&](int buf, int ks) {
        const int ci0 = ks * 64;
        char* dst = lds + buf * 65536;
        #pragma unroll
        for (int i = 0; i < 8; ++i) {
            int o = (wave * 8 + i) * 1024 + lane * 16;
            const char* src;
            if (o < 32768) {                       // A: waves 0..3
                int row = o >> 7;
                int inner = (o & 127) ^ ((row & 7) << 4);
                int grow = GATHER ? ids_src[row] : (m0 + row);
                src = hbase + (size_t)grow * 512 + ci0 * 2 + inner;
            } else {                               // B: waves 4..7
                int bo = o - 32768;
                int corow = bo >> 7;
                int inner = (bo & 127) ^ ((corow & 7) << 4);
                src = wbase + (size_t)corow * 512 + ci0 * 2 + inner;
            }
            gload16(src, dst + o);
        }
    };

    auto COMPUTE = [&](int buf) {
        const char* A = lds + buf * 65536;
        const char* B = A + 32768;
        #pragma unroll
        for (int kk = 0; kk < 64; kk += 32) {
            int kl = kk + 8 * (lane >> 4);
            bf16x8 af[8], bfr[4];
            #pragma unroll
            for (int mi = 0; mi < 8; ++mi) {
                int row = wm * 128 + 16 * mi + (lane & 15);
                af[mi] = *(const bf16x8*)(A + row * 128 + ((2 * kl) ^ ((row & 7) << 4)));
            }
            #pragma unroll
            for (int ni = 0; ni < 4; ++ni) {
                int corow = wn * 64 + 16 * ni + (lane & 15);
                bfr[ni] = *(const bf16x8*)(B + corow * 128 + ((2 * kl) ^ ((corow & 7) << 4)));
            }
            #pragma unroll
            for (int mi = 0; mi < 8; ++mi)
                #pragma unroll
                for (int ni = 0; ni < 4; ++ni)
                    acc[mi][ni] = __builtin_amdgcn_mfma_f32_16x16x32_bf16(af[mi], bfr[ni], acc[mi][ni], 0, 0, 0);
        }
    };

    STAGE(0, 0);
    __syncthreads();
    int cur = 0;
    #pragma unroll
    for (int ks = 0; ks < 4; ++ks) {
        if (ks < 3) STAGE(cur ^ 1, ks + 1);   // issue next-tile loads first
        COMPUTE(cur);                          // MFMA overlaps load flight
        __syncthreads();
        cur ^= 1;
    }

    // epilogue: pair-packed bf16 plain stores
    const int rq = 4 * (lane >> 4);
    const int colo = lane & 15;
    #pragma unroll
    for (int mi = 0; mi < 8; ++mi)
        #pragma unroll
        for (int ni = 0; ni < 4; ++ni) {
            int col = wn * 64 + 16 * ni + colo;
            #pragma unroll
            for (int r = 0; r < 4; ++r) {
                float v = acc[mi][ni][r];
                float o = __shfl_xor(v, 1);
                if ((lane & 1) == 0) {
                    unsigned pk = (unsigned)f2bf(v) | ((unsigned)f2bf(o) << 16);
                    int rl = wm * 128 + 16 * mi + rq + r;
                    if (!GATHER) {
                        *(unsigned*)&yb[(size_t)(m0 + rl) * CHID + col] = pk;
                    } else {
                        int g = tile * 256 + rl;
                        if (g < c)
                            *(unsigned*)&yb[((size_t)k26 * CAP + g) * CHID + col] = pk;
                    }
                }
            }
        }
}

// ---------------------------------------------------------------------------
// Combine + BN partial stats: Y[n] += sum_j buf[nbrEnt[n][j]]; write Y;
// per-block channel partials -> part[blk][512] (plain stores, no atomics).
// Grid: CBLK blocks x 32 rows. Thread t: row-slot t>>5, col octet (t&31)*8.
// ---------------------------------------------------------------------------
__global__ __launch_bounds__(256)
void combine_stats(unsigned short* __restrict__ Yb,
                   const unsigned short* __restrict__ buf,
                   const int* __restrict__ nbrEnt,
                   const unsigned char* __restrict__ nbrCnt,
                   float* __restrict__ part) {
    __shared__ float ssum[8][256];
    __shared__ float ssq[8][256];
    const int tid = threadIdx.x;
    const int grp = tid >> 5;
    const int c0  = (tid & 31) * 8;
    float s[8] = {}, s2[8] = {};
    const int row0 = blockIdx.x * 32;
    for (int it = 0; it < 4; ++it) {
        int row = row0 + it * 8 + grp;
        size_t off = (size_t)row * CHID + c0;
        u16x8 y = *(const u16x8*)&Yb[off];
        float v[8];
        #pragma unroll
        for (int q = 0; q < 8; ++q) v[q] = bf2f(y[q]);
        int cnt = nbrCnt[row];
        for (int j = 0; j < cnt; ++j) {
            int e = nbrEnt[row * 32 + j];
            u16x8 b = *(const u16x8*)&buf[(size_t)e * CHID + c0];
            #pragma unroll
            for (int q = 0; q < 8; ++q) v[q] += bf2f(b[q]);
        }
        u16x8 o;
        #pragma unroll
        for (int q = 0; q < 8; ++q) {
            o[q] = f2bf(v[q]);
            s[q] += v[q];
            s2[q] += v[q] * v[q];
        }
        *(u16x8*)&Yb[off] = o;
    }
    #pragma unroll
    for (int q = 0; q < 8; ++q) {
        ssum[grp][c0 + q] = s[q];
        ssq[grp][c0 + q]  = s2[q];
    }
    __syncthreads();
    float ts = 0.f, tq = 0.f;
    #pragma unroll
    for (int g = 0; g < 8; ++g) { ts += ssum[g][tid]; tq += ssq[g][tid]; }
    part[(size_t)blockIdx.x * 512 + tid]       = ts;
    part[(size_t)blockIdx.x * 512 + 256 + tid] = tq;
}

// ---------------------------------------------------------------------------
// BN partial stats only (layer 0): same mapping, no BUF, no Y-write.
// ---------------------------------------------------------------------------
__global__ __launch_bounds__(256)
void bn_stats_vec(const unsigned short* __restrict__ Yb, float* __restrict__ part) {
    __shared__ float ssum[8][256];
    __shared__ float ssq[8][256];
    const int tid = threadIdx.x;
    const int grp = tid >> 5;
    const int c0  = (tid & 31) * 8;
    float s[8] = {}, s2[8] = {};
    const int row0 = blockIdx.x * 32;
    for (int it = 0; it < 4; ++it) {
        int row = row0 + it * 8 + grp;
        u16x8 y = *(const u16x8*)&Yb[(size_t)row * CHID + c0];
        #pragma unroll
        for (int q = 0; q < 8; ++q) {
            float v = bf2f(y[q]);
            s[q] += v; s2[q] += v * v;
        }
    }
    #pragma unroll
    for (int q = 0; q < 8; ++q) {
        ssum[grp][c0 + q] = s[q];
        ssq[grp][c0 + q]  = s2[q];
    }
    __syncthreads();
    float ts = 0.f, tq = 0.f;
    #pragma unroll
    for (int g = 0; g < 8; ++g) { ts += ssum[g][tid]; tq += ssq[g][tid]; }
    part[(size_t)blockIdx.x * 512 + tid]       = ts;
    part[(size_t)blockIdx.x * 512 + 256 + tid] = tq;
}

// ---------------------------------------------------------------------------
// Reduce partials: st[c] = sum over CBLK blocks of part[b][c].
// Grid 32 x 256: c = gt&511, chunk = gt>>9 (16 chunks of 128 blocks).
// st pre-zeroed; 16 atomics per channel.
// ---------------------------------------------------------------------------
__global__ void reduce_stats(const float* __restrict__ part, float* __restrict__ st) {
    int gt = blockIdx.x * 256 + threadIdx.x;
    int c = gt & 511;
    int chunk = gt >> 9;
    float s = 0.f;
    for (int i = 0; i < CBLK / 16; ++i)
        s += part[(size_t)(chunk * (CBLK / 16) + i) * 512 + c];
    unsafeAtomicAdd(&st[c], s);
}

// ---------------------------------------------------------------------------
// BN apply (+optional residual) + ReLU -> bf16, vectorized u16x8.
// Grid CBLK x 32 rows; thread: row-slot tid>>5, col octet (tid&31)*8.
// ---------------------------------------------------------------------------
__global__ __launch_bounds__(256)
void bn_apply(const unsigned short* __restrict__ yb, const float* __restrict__ st,
              const float* __restrict__ g, const float* __restrict__ b,
              const unsigned short* __restrict__ res, unsigned short* __restrict__ hout) {
    const int tid = threadIdx.x;
    const int grp = tid >> 5;
    const int c0  = (tid & 31) * 8;
    float sc[8], bi[8];
    #pragma unroll
    for (int q = 0; q < 8; ++q) {
        float mean = st[c0 + q] * (1.f / NPTS);
        float var  = st[256 + c0 + q] * (1.f / NPTS) - mean * mean;
        float rstd = rsqrtf(var + 1e-5f);
        sc[q] = rstd * g[c0 + q];
        bi[q] = b[c0 + q] - mean * sc[q];
    }
    const int row0 = blockIdx.x * 32;
    for (int it = 0; it < 4; ++it) {
        int row = row0 + it * 8 + grp;
        size_t off = (size_t)row * CHID + c0;
        u16x8 y = *(const u16x8*)&yb[off];
        u16x8 o;
        if (res) {
            u16x8 rr = *(const u16x8*)&res[off];
            #pragma unroll
            for (int q = 0; q < 8; ++q) {
                float v = bf2f(y[q]) * sc[q] + bi[q] + bf2f(rr[q]);
                o[q] = f2bf(fmaxf(v, 0.f));
            }
        } else {
            #pragma unroll
            for (int q = 0; q < 8; ++q) {
                float v = bf2f(y[q]) * sc[q] + bi[q];
                o[q] = f2bf(fmaxf(v, 0.f));
            }
        }
        *(u16x8*)&hout[off] = o;
    }
}

// ---------------------------------------------------------------------------
// Output GEMM: out[N][128] = h[N][256] @ w_out. 128x128 tile, 4 waves 2x2.
// ---------------------------------------------------------------------------
__global__ __launch_bounds__(256, 2)
void gemm_out(const unsigned short* __restrict__ hin, const unsigned short* __restrict__ wop,
              float* __restrict__ out) {
    __shared__ __align__(16) char lds[16384 + 16384];
    const int tid = threadIdx.x, lane = tid & 63, wave = tid >> 6;
    const int m0 = blockIdx.x * 128;
    const char* hb = (const char*)hin;
    const char* wb = (const char*)wop;
    f32x4 acc[4][4] = {};
    for (int ks = 0; ks < 4; ++ks) {
        int ci0 = ks * 64;
        __syncthreads();
        for (int i = 0; i < 8; ++i) {
            int chunk = wave * 8 + i;
            int o = chunk * 1024 + lane * 16;
            const char* src;
            if (o < 16384) {
                int row = o >> 7;
                int k2 = (o & 127) ^ ((row & 7) << 4);
                src = hb + (size_t)(m0 + row) * 512 + ci0 * 2 + k2;
            } else {
                int bo = o - 16384;
                int corow = bo >> 7;
                int k2 = (bo & 127) ^ ((corow & 7) << 4);
                src = wb + (size_t)corow * 512 + ci0 * 2 + k2;
            }
            gload16(src, lds + chunk * 1024);
        }
        __syncthreads();
        const char* A = lds;
        const char* B = lds + 16384;
        const int wm = wave >> 1, wn = wave & 1;
        for (int kk = 0; kk < 64; kk += 32) {
            int kl = kk + 8 * (lane >> 4);
            bf16x8 af[4], bfr[4];
            for (int mi = 0; mi < 4; ++mi) {
                int row = 64 * wm + 16 * mi + (lane & 15);
                af[mi] = *(const bf16x8*)(A + row * 128 + ((2 * kl) ^ ((row & 7) << 4)));
            }
            for (int ni = 0; ni < 4; ++ni) {
                int corow = 64 * wn + 16 * ni + (lane & 15);
                bfr[ni] = *(const bf16x8*)(B + corow * 128 + ((2 * kl) ^ ((corow & 7) << 4)));
            }
            for (int mi = 0; mi < 4; ++mi)
                for (int ni = 0; ni < 4; ++ni)
                    acc[mi][ni] = __builtin_amdgcn_mfma_f32_16x16x32_bf16(af[mi], bfr[ni], acc[mi][ni], 0, 0, 0);
        }
    }
    const int wm = wave >> 1, wn = wave & 1;
    for (int mi = 0; mi < 4; ++mi)
        for (int ni = 0; ni < 4; ++ni) {
            int col = 64 * wn + 16 * ni + (lane & 15);
            for (int r = 0; r < 4; ++r) {
                int row = m0 + 64 * wm + 16 * mi + 4 * (lane >> 4) + r;
                out[(size_t)row * 128 + col] = acc[mi][ni][r];
            }
        }
}

// ---------------------------------------------------------------------------
// Workspace layout (bytes); total ~192 MiB
// ---------------------------------------------------------------------------
static const size_t OFF_Y    = 0;                         // bf16 Y: 33.5 MB
static const size_t OFF_HA   = OFF_Y   + (size_t)NPTS * CHID * 2;
static const size_t OFF_HR   = OFF_HA  + (size_t)NPTS * CHID * 2;
static const size_t OFF_WP   = OFF_HR  + (size_t)NPTS * CHID * 2;
static const size_t OFF_WOP  = OFF_WP  + (size_t)8 * 27 * 65536 * 2;
static const size_t OFF_WIN  = OFF_WOP + (size_t)128 * 256 * 2;
static const size_t OFF_ST   = OFF_WIN + (size_t)256 * 128 * 2;
static const size_t OFF_CNT  = OFF_ST  + 9 * 512 * 4;
static const size_t OFF_FLAG = OFF_CNT + 112;
static const size_t OFF_SRC  = OFF_CNT + 128;
static const size_t OFF_BLK  = OFF_SRC + (size_t)26 * CAP * 4;
static const size_t OFF_BAS  = OFF_BLK + (size_t)26 * LBLK * 4;
static const size_t OFF_NBE  = OFF_BAS + (size_t)26 * LBLK * 4;   // [N][32] int
static const size_t OFF_NBC  = OFF_NBE + (size_t)NPTS * 32 * 4;   // [N] u8
static const size_t OFF_PART = OFF_NBC + (size_t)NPTS;            // [CBLK][512] f32
static const size_t OFF_BUF  = OFF_PART + (size_t)CBLK * 512 * 4; // [26*CAP][256] bf16

extern "C" void kernel_launch(void* const* d_in, const int* in_sizes, int n_in,
                              void* d_out, int out_size, void* d_ws, size_t ws_size,
                              hipStream_t stream) {
    const float* feats = (const float*)d_in[0];
    const float* w_in  = (const float*)d_in[1];
    const float* g_in  = (const float*)d_in[2];
    const float* b_in  = (const float*)d_in[3];
    const float* w_res = (const float*)d_in[4];
    const float* g_res = (const float*)d_in[5];
    const float* b_res = (const float*)d_in[6];
    const float* w_out = (const float*)d_in[7];
    const int*   nidx  = (const int*)d_in[8];
    const void*  nmask = (const void*)d_in[9];

    char* ws = (char*)d_ws;
    unsigned short* Yb   = (unsigned short*)(ws + OFF_Y);
    unsigned short* HA   = (unsigned short*)(ws + OFF_HA);
    unsigned short* HR   = (unsigned short*)(ws + OFF_HR);
    unsigned short* WP   = (unsigned short*)(ws + OFF_WP);
    unsigned short* WOP  = (unsigned short*)(ws + OFF_WOP);
    unsigned short* WIN  = (unsigned short*)(ws + OFF_WIN);
    float*          ST   = (float*)(ws + OFF_ST);
    int*            CNT  = (int*)(ws + OFF_CNT);
    int*            MFLG = (int*)(ws + OFF_FLAG);
    int*            SRCL = (int*)(ws + OFF_SRC);
    int*            BLKC = (int*)(ws + OFF_BLK);
    int*            BASE = (int*)(ws + OFF_BAS);
    int*            NBE  = (int*)(ws + OFF_NBE);
    unsigned char*  NBC  = (unsigned char*)(ws + OFF_NBC);
    float*          PART = (float*)(ws + OFF_PART);
    unsigned short* BUF  = (unsigned short*)(ws + OFF_BUF);

    // zero BN stats (9 layers x 512 f32) + CNT slab + mask-dtype flag
    hipMemsetAsync(ws + OFF_ST, 0, 9 * 512 * 4 + 128, stream);

    detect_mask<<<64, 256, 0, stream>>>((const unsigned char*)nmask, MFLG);
    pack_w   <<<dim3(216, 16), 256, 0, stream>>>(w_res, WP);
    pack_wout<<<dim3(2, 4),    256, 0, stream>>>(w_out, WOP);
    pack_win <<<dim3(4, 2),    256, 0, stream>>>(w_in, WIN);

    count_lists<<<LBLK, 256, 0, stream>>>(nmask, MFLG, BLKC);
    scan_lists <<<1, 64, 0, stream>>>(BLKC, BASE, CNT);
    fill_lists <<<LBLK, 256, 0, stream>>>(nidx, nmask, MFLG, BASE, SRCL, NBE, NBC);

    convin_gemm<<<NPTS / 64, 256, 0, stream>>>(feats, WIN, nidx, nmask, MFLG, Yb);
    bn_stats_vec<<<CBLK, 256, 0, stream>>>(Yb, PART);
    reduce_stats<<<32, 256, 0, stream>>>(PART, ST);
    bn_apply<<<CBLK, 256, 0, stream>>>(Yb, ST, g_in, b_in, nullptr, HA);

    for (int c8 = 0; c8 < 8; ++c8) {
        const unsigned short* hin = (c8 & 1) ? HR : HA;
        const unsigned short* wbase = WP + (size_t)c8 * 27 * 65536;
        float* st = ST + (size_t)(1 + c8) * 512;
        conv_gemm<false><<<NPTS / 256, 512, 0, stream>>>(hin, wbase, Yb, nullptr, nullptr);
        conv_gemm<true><<<dim3(26, CAP / 256), 512, 0, stream>>>(hin, wbase, BUF, CNT, SRCL);
        combine_stats<<<CBLK, 256, 0, stream>>>(Yb, BUF, NBE, NBC, PART);
        reduce_stats<<<32, 256, 0, stream>>>(PART, st);
        if (c8 & 1) {
            bn_apply<<<CBLK, 256, 0, stream>>>(Yb, st, g_res + c8 * 256, b_res + c8 * 256, HA, HA);
        } else {
            bn_apply<<<CBLK, 256, 0, stream>>>(Yb, st, g_res + c8 * 256, b_res + c8 * 256, nullptr, HR);
        }
    }

    gemm_out<<<NPTS / 128, 256, 0, stream>>>(HA, WOP, (float*)d_out);
}